// Round 1
// baseline (615.034 us; speedup 1.0000x reference)
//
#include <hip/hip_runtime.h>
#include <hip/hip_cooperative_groups.h>
#include <math.h>

namespace cg = cooperative_groups;

// R7: single cooperative kernel. The 7-dispatch chain was dominated by
// per-dispatch launch/drain overhead (sum of actual work ~40 µs vs 305 µs
// measured). One kernel, 5 grid.sync()s. Flag arrays + memset replaced by
// deterministic per-block LDS dedup of the (tiny) L2 edge list.
#define FAMAX 64     // dst-frontier assets (expected ~11)
#define FCMAX 32     // dst-frontier creators (expected ~1)
#define FLMAX 32     // dst-frontier licensees (expected ~2)
#define N1MAX 512    // layer-1 edges into frontier (expected ~125)
#define N2MAX 128    // layer-2 edges into query (expected ~9)
#define NBLK  256
#define NTHR  256

struct Inputs {
  const float *x_asset, *x_creator, *x_licensee;
  const float *Wp_a,*bp_a,*Wp_c,*bp_c,*Wp_l,*bp_l;
  const float *Wl1,*bl1,*Wr1,*br1,*We1,*att1,*bias1;
  const float *Wl2,*bl2,*Wr2,*br2,*We2,*att2,*bias2;
  const float *Wc1,*bc1,*Wc2,*bc2;
};

struct Edges {
  const int *cb_s,*cb_d;  const float* ea_cb;  int Ecb;
  const int *lt_s,*lt_d;  const float* ea_lt;  int Elt;
  const int *sim_s,*sim_d;const float* ea_sim; int Esim;
  const int *fw_s,*fw_d;  const float* ea_fw;  int Efw;
  const int *rcb_s,*rcb_d;const float* ea_rcb; int Ercb;
  const int *rlt_s,*rlt_d;const float* ea_rlt; int Erlt;
};

struct WSP {
  int* cnt;             // [0]=n_l2e [4]=n_l1e
  int* l2rel; int* l2src; float* l2ea;
  int* l1rel; int* l1src; int* l1dslot; float* l1ea;
  float* xl1e;                // [N1MAX][256]
  float* logit1;              // [N1MAX][2]
  float *x1a,*x1c,*x1l;       // layer-1 outputs [F*MAX][128]
  float* xl2e;                // [N2MAX][128]
};

__device__ __forceinline__ float leaky(float x){ return x > 0.f ? x : 0.2f*x; }

// 128-d projection of `node` of `type` into LDS h0[] using 256 threads.
// type: 0=Asset (512-d input, split-K by 2), 1=Creator, 2=Licensee.
__device__ __forceinline__ void proj256(int type, int node, const Inputs& in,
                                        float* h0, float* xs, float* part){
  int t = threadIdx.x;
  if (type == 0){
    xs[t]       = in.x_asset[(size_t)node*512 + t];
    xs[t + 256] = in.x_asset[(size_t)node*512 + t + 256];
    __syncthreads();
    int j = t & 127, g2 = t >> 7;
    float acc = 0.f;
    const float* W = in.Wp_a + (size_t)g2*256*128 + j;
    const float* xg = xs + g2*256;
    for (int k=0;k<256;k++) acc = fmaf(xg[k], W[(size_t)k*128], acc);
    part[t] = acc;
    __syncthreads();
    if (t < 128) h0[t] = in.bp_a[t] + part[t] + part[128 + t];
  } else if (type == 1){
    if (t < 128)
      h0[t] = in.bp_c[t] + in.x_creator[node*2]*in.Wp_c[t]
            + in.x_creator[node*2+1]*in.Wp_c[128+t];
  } else {
    if (t < 128)
      h0[t] = in.bp_l[t] + in.x_licensee[node]*in.Wp_l[t];
  }
  __syncthreads();
}

__global__ void __launch_bounds__(NTHR)
mega(Inputs in, Edges eg, WSP w, const int* qptr, float* outp){
  __shared__ float xs[512];
  __shared__ float part[256];
  __shared__ float h0s[128];
  __shared__ float h0d[128];
  __shared__ float red[256];
  __shared__ float s_xr2[4*128];
  __shared__ int   s_fa[FAMAX];
  __shared__ int   s_fc[FCMAX];
  __shared__ int   s_fl[FLMAX];
  __shared__ int   s_nf[3];
  __shared__ int   s_l2slot[N2MAX];
  __shared__ int   s_l2src[N2MAX];
  __shared__ int   s_key[N1MAX];
  __shared__ float s_lg0[N1MAX];
  __shared__ float s_lg1[N1MAX];

  cg::grid_group grid = cg::this_grid();
  const int t = threadIdx.x;
  const int b = blockIdx.x;
  const int gtid = b*NTHR + t;
  const int gstride = NBLK*NTHR;
  const int q = qptr[0];

  // ---- P0: zero counters ----
  if (b == 0 && t < 16) w.cnt[t] = 0;
  grid.sync();

  // ---- P1: scan Asset-targeting relations for dst == q -> L2 edge list ----
  {
    int total = eg.Esim + eg.Efw + eg.Ercb + eg.Erlt;
    for (int i = gtid; i < total; i += gstride){
      int j = i, rel; const int *sp,*dp; const float* ep;
      if (j < eg.Esim){ rel=2; sp=eg.sim_s; dp=eg.sim_d; ep=eg.ea_sim; }
      else { j -= eg.Esim;
        if (j < eg.Efw){ rel=3; sp=eg.fw_s; dp=eg.fw_d; ep=eg.ea_fw; }
        else { j -= eg.Efw;
          if (j < eg.Ercb){ rel=4; sp=eg.rcb_s; dp=eg.rcb_d; ep=eg.ea_rcb; }
          else { j -= eg.Ercb; rel=5; sp=eg.rlt_s; dp=eg.rlt_d; ep=eg.ea_rlt; }
        }
      }
      if (dp[j] == q){
        int k = atomicAdd(&w.cnt[0], 1);
        if (k < N2MAX){ w.l2rel[k]=rel; w.l2src[k]=sp[j]; w.l2ea[k]=ep[j]; }
      }
    }
  }
  grid.sync();

  // ---- P2: per-block deterministic dedup of L2 srcs -> LDS frontier lists.
  // Every block reads the SAME global list, so every block derives the SAME
  // slot assignment. q is always asset slot 0.
  {
    int n2 = min(w.cnt[0], N2MAX);
    for (int i = t; i < n2; i += NTHR){
      s_key[i]   = w.l2rel[i];
      s_l2src[i] = w.l2src[i];
    }
    __syncthreads();
    if (t == 0){
      int nfa = 0, nfc = 0, nfl = 0;
      s_fa[nfa++] = q;
      for (int i=0;i<n2;i++){
        int rel = s_key[i], src = s_l2src[i];
        int s = -1;
        if (rel <= 3){
          for (int k=0;k<nfa;k++) if (s_fa[k]==src){ s=k; break; }
          if (s < 0 && nfa < FAMAX){ s = nfa; s_fa[nfa++] = src; }
        } else if (rel == 4){
          for (int k=0;k<nfc;k++) if (s_fc[k]==src){ s=k; break; }
          if (s < 0 && nfc < FCMAX){ s = nfc; s_fc[nfc++] = src; }
        } else {
          for (int k=0;k<nfl;k++) if (s_fl[k]==src){ s=k; break; }
          if (s < 0 && nfl < FLMAX){ s = nfl; s_fl[nfl++] = src; }
        }
        s_l2slot[i] = s;  // -1 on frontier-capacity overflow
      }
      s_nf[0]=nfa; s_nf[1]=nfc; s_nf[2]=nfl;
    }
    __syncthreads();
  }

  // ---- P3: scan all 6 relations, dst in frontier -> L1 edge list ----
  {
    int nfa = s_nf[0], nfc = s_nf[1], nfl = s_nf[2];
    int total = eg.Ecb+eg.Elt+eg.Esim+eg.Efw+eg.Ercb+eg.Erlt;
    for (int i = gtid; i < total; i += gstride){
      int j = i, rel; const int *sp,*dp; const float* ep;
      if (j < eg.Ecb){ rel=0; sp=eg.cb_s; dp=eg.cb_d; ep=eg.ea_cb; }
      else { j -= eg.Ecb;
      if (j < eg.Elt){ rel=1; sp=eg.lt_s; dp=eg.lt_d; ep=eg.ea_lt; }
      else { j -= eg.Elt;
      if (j < eg.Esim){ rel=2; sp=eg.sim_s; dp=eg.sim_d; ep=eg.ea_sim; }
      else { j -= eg.Esim;
      if (j < eg.Efw){ rel=3; sp=eg.fw_s; dp=eg.fw_d; ep=eg.ea_fw; }
      else { j -= eg.Efw;
      if (j < eg.Ercb){ rel=4; sp=eg.rcb_s; dp=eg.rcb_d; ep=eg.ea_rcb; }
      else { j -= eg.Ercb; rel=5; sp=eg.rlt_s; dp=eg.rlt_d; ep=eg.ea_rlt; }}}}}
      int d = dp[j];
      int slot = -1;
      if (rel == 0){ for (int k=0;k<nfc;k++) if (s_fc[k]==d){ slot=k; break; } }
      else if (rel == 1){ for (int k=0;k<nfl;k++) if (s_fl[k]==d){ slot=k; break; } }
      else { for (int k=0;k<nfa;k++) if (s_fa[k]==d){ slot=k; break; } }
      if (slot >= 0){
        int k = atomicAdd(&w.cnt[4], 1);
        if (k < N1MAX){ w.l1rel[k]=rel; w.l1src[k]=sp[j]; w.l1dslot[k]=slot; w.l1ea[k]=ep[j]; }
      }
    }
  }
  grid.sync();

  // ---- P4: per-L1-edge layer-1 compute (old k3), edge-parallel ----
  {
    int n1 = min(w.cnt[4], N1MAX);
    for (int e = b; e < n1; e += NBLK){
      int rel = w.l1rel[e], src = w.l1src[e], dslot = w.l1dslot[e];
      float ea = w.l1ea[e];
      int stype = (rel <= 3) ? 0 : (rel == 4 ? 1 : 2);
      int dtype = (rel == 0) ? 1 : (rel == 1 ? 2 : 0);
      int dnode = (rel == 0) ? s_fc[dslot] : (rel == 1 ? s_fl[dslot] : s_fa[dslot]);
      proj256(stype, src, in, h0s, xs, part);
      float xl1 = in.bl1[rel*256 + t];
      {
        const float* W = in.Wl1 + (size_t)rel*128*256 + t;
        for (int c=0;c<128;c++) xl1 = fmaf(h0s[c], W[(size_t)c*256], xl1);
      }
      w.xl1e[(size_t)e*256 + t] = xl1;
      proj256(dtype, dnode, in, h0d, xs, part);
      float xr1 = in.br1[rel*256 + t];
      {
        const float* W = in.Wr1 + (size_t)rel*128*256 + t;
        for (int c=0;c<128;c++) xr1 = fmaf(h0d[c], W[(size_t)c*256], xr1);
      }
      int h = t >> 7, c = t & 127;
      float ev = leaky(xl1 + xr1 + ea*in.We1[rel*256 + t]);
      red[t] = ev * in.att1[(rel*2 + h)*128 + c];
      __syncthreads();
      for (int s=64; s>0; s>>=1){ if (c < s) red[t] += red[t+s]; __syncthreads(); }
      if (c == 0) w.logit1[e*2 + h] = red[t];
      __syncthreads();
    }
  }
  grid.sync();

  // ---- P5: per-frontier-node segment softmax + aggregate (old k4),
  // with edge keys/logits preloaded to LDS ----
  {
    int n1 = min(w.cnt[4], N1MAX);
    int nfa = s_nf[0], nfc = s_nf[1], nfl = s_nf[2];
    int nf = nfa + nfc + nfl;
    if (b < nf){
      for (int i = t; i < n1; i += NTHR){
        s_key[i] = (w.l1rel[i] << 8) | w.l1dslot[i];
        s_lg0[i] = w.logit1[i*2];
        s_lg1[i] = w.logit1[i*2+1];
      }
      __syncthreads();
      if (t < 128){
        int type, slot;
        if (b < nfa){ type=0; slot=b; }
        else if (b < nfa+nfc){ type=1; slot=b-nfa; }
        else { type=2; slot=b-nfa-nfc; }
        int r0, r1;
        if (type==0){ r0=2; r1=5; } else if (type==1){ r0=0; r1=0; } else { r0=1; r1=1; }
        float out = 0.f;
        for (int r=r0; r<=r1; r++){
          out += in.bias1[r*128 + t];
          int key = (r<<8) | slot;
          float m0=-INFINITY, m1=-INFINITY;
          for (int i=0;i<n1;i++){
            if (s_key[i]==key){
              m0 = fmaxf(m0, s_lg0[i]);
              m1 = fmaxf(m1, s_lg1[i]);
            }
          }
          if (m0 == -INFINITY) continue;
          float d0=0.f, d1=0.f, a0=0.f, a1=0.f;
          for (int i=0;i<n1;i++){
            if (s_key[i]==key){
              float e0 = expf(s_lg0[i] - m0);
              float e1 = expf(s_lg1[i] - m1);
              d0 += e0; d1 += e1;
              a0 = fmaf(e0, w.xl1e[(size_t)i*256 + t],       a0);
              a1 = fmaf(e1, w.xl1e[(size_t)i*256 + 128 + t], a1);
            }
          }
          out += 0.5f*(a0/(d0+1e-16f) + a1/(d1+1e-16f));
        }
        float v = fmaxf(out, 0.f);
        if (type==0) w.x1a[slot*128 + t] = v;
        else if (type==1) w.x1c[slot*128 + t] = v;
        else w.x1l[slot*128 + t] = v;
      }
    }
  }
  grid.sync();

  // ---- P6: layer-2 + classifier, block 0 only (old k5b + k5c fused).
  // xr2 depends only on (rel, x1[q]) -> precompute 4 GEMVs instead of per-edge.
  if (b == 0){
    int n2 = min(w.cnt[0], N2MAX);
    // preload edge metadata
    for (int i = t; i < n2; i += NTHR){
      s_key[i] = w.l2rel[i];
      s_lg1[i] = w.l2ea[i];
    }
    if (t < 128) h0s[t] = w.x1a[t];   // x1 of q (slot 0)
    __syncthreads();
    int j = t & 127, g = t >> 7;
    // xr2 for rels 2..5 (split-K over 2 thread groups)
    for (int r=2; r<=5; r++){
      const float* W = in.Wr2 + (size_t)r*128*128 + j;
      float acc = 0.f;
      for (int c=g*64; c<g*64+64; c++) acc = fmaf(h0s[c], W[(size_t)c*128], acc);
      part[t] = acc;
      __syncthreads();
      if (t < 128) s_xr2[(r-2)*128 + t] = in.br2[r*128 + t] + part[t] + part[t+128];
      __syncthreads();
    }
    // per-edge xl2 + logit
    for (int i=0; i<n2; i++){
      int rel = s_key[i];
      int slot = s_l2slot[i];
      float ea = s_lg1[i];
      const float* xb = (rel <= 3) ? w.x1a : (rel == 4 ? w.x1c : w.x1l);
      if (t < 128) h0d[t] = (slot >= 0) ? xb[(size_t)slot*128 + t] : 0.f;
      __syncthreads();
      const float* W = in.Wl2 + (size_t)rel*128*128 + j;
      float acc = 0.f;
      for (int c=g*64; c<g*64+64; c++) acc = fmaf(h0d[c], W[(size_t)c*128], acc);
      part[t] = acc;
      __syncthreads();
      if (t < 128){
        float xl2 = in.bl2[rel*128 + t] + part[t] + part[t+128];
        w.xl2e[(size_t)i*128 + t] = xl2;
        float ev = leaky(xl2 + s_xr2[(rel-2)*128 + t] + ea*in.We2[rel*128 + t]);
        red[t] = ev * in.att2[rel*128 + t];
      }
      __syncthreads();
      for (int s=64; s>0; s>>=1){ if (t < s) red[t] += red[t+s]; __syncthreads(); }
      if (t == 0) s_lg0[i] = (slot >= 0) ? red[0] : -INFINITY;
      __syncthreads();
    }
    // segment softmax + aggregate + relu -> classifier head
    if (t < 128){
      float o = 0.f;
      for (int r=2; r<=5; r++){
        o += in.bias2[r*128 + t];
        float m = -INFINITY;
        for (int i=0;i<n2;i++) if (s_key[i]==r) m = fmaxf(m, s_lg0[i]);
        if (m == -INFINITY) continue;
        float dsum = 0.f, acc = 0.f;
        for (int i=0;i<n2;i++) if (s_key[i]==r){
          float e = expf(s_lg0[i] - m);
          dsum += e;
          acc = fmaf(e, w.xl2e[(size_t)i*128 + t], acc);
        }
        o += acc/(dsum + 1e-16f);
      }
      h0d[t] = fmaxf(o, 0.f);  // x2
    }
    __syncthreads();
    if (t < 128){
      float acc = in.bc1[t];
      for (int c=0;c<128;c++) acc = fmaf(h0d[c], in.Wc1[c*128 + t], acc);
      red[t] = fmaxf(acc, 0.f);  // hidden
    }
    __syncthreads();
    if (t < 3){
      float r = in.bc2[t];
      for (int c=0;c<128;c++) r = fmaf(red[c], in.Wc2[c*3 + t], r);
      outp[t] = r;
    }
  }
}

extern "C" void kernel_launch(void* const* d_in, const int* in_sizes, int n_in,
                              void* d_out, int out_size, void* d_ws, size_t ws_size,
                              hipStream_t stream){
  Inputs in;
  in.x_asset   = (const float*)d_in[0];
  in.x_creator = (const float*)d_in[1];
  in.x_licensee= (const float*)d_in[2];
  Edges eg;
  eg.cb_s =(const int*)d_in[3];  eg.cb_d =(const int*)d_in[4];  eg.ea_cb =(const float*)d_in[5];  eg.Ecb = in_sizes[3];
  eg.lt_s =(const int*)d_in[6];  eg.lt_d =(const int*)d_in[7];  eg.ea_lt =(const float*)d_in[8];  eg.Elt = in_sizes[6];
  eg.sim_s=(const int*)d_in[9];  eg.sim_d=(const int*)d_in[10]; eg.ea_sim=(const float*)d_in[11]; eg.Esim= in_sizes[9];
  eg.fw_s =(const int*)d_in[12]; eg.fw_d =(const int*)d_in[13]; eg.ea_fw =(const float*)d_in[14]; eg.Efw = in_sizes[12];
  eg.rcb_s=(const int*)d_in[15]; eg.rcb_d=(const int*)d_in[16]; eg.ea_rcb=(const float*)d_in[17]; eg.Ercb= in_sizes[15];
  eg.rlt_s=(const int*)d_in[18]; eg.rlt_d=(const int*)d_in[19]; eg.ea_rlt=(const float*)d_in[20]; eg.Erlt= in_sizes[18];
  in.Wp_a=(const float*)d_in[21]; in.bp_a=(const float*)d_in[22];
  in.Wp_c=(const float*)d_in[23]; in.bp_c=(const float*)d_in[24];
  in.Wp_l=(const float*)d_in[25]; in.bp_l=(const float*)d_in[26];
  in.Wl1=(const float*)d_in[27]; in.bl1=(const float*)d_in[28];
  in.Wr1=(const float*)d_in[29]; in.br1=(const float*)d_in[30];
  in.We1=(const float*)d_in[31]; in.att1=(const float*)d_in[32]; in.bias1=(const float*)d_in[33];
  in.Wl2=(const float*)d_in[34]; in.bl2=(const float*)d_in[35];
  in.Wr2=(const float*)d_in[36]; in.br2=(const float*)d_in[37];
  in.We2=(const float*)d_in[38]; in.att2=(const float*)d_in[39]; in.bias2=(const float*)d_in[40];
  in.Wc1=(const float*)d_in[41]; in.bc1=(const float*)d_in[42];
  in.Wc2=(const float*)d_in[43]; in.bc2=(const float*)d_in[44];
  const int* qptr = (const int*)d_in[45];
  float* outp = (float*)d_out;

  char* p = (char*)d_ws;
  auto carve = [&](size_t n)->char*{ char* r = p; p += ((n + 255) & ~(size_t)255); return r; };
  WSP w;
  w.cnt  = (int*)carve(16*4);
  w.l2rel=(int*)carve(N2MAX*4); w.l2src=(int*)carve(N2MAX*4); w.l2ea=(float*)carve(N2MAX*4);
  w.l1rel=(int*)carve(N1MAX*4); w.l1src=(int*)carve(N1MAX*4); w.l1dslot=(int*)carve(N1MAX*4); w.l1ea=(float*)carve(N1MAX*4);
  w.xl1e=(float*)carve((size_t)N1MAX*256*4);
  w.logit1=(float*)carve((size_t)N1MAX*2*4);
  w.x1a=(float*)carve((size_t)FAMAX*128*4);
  w.x1c=(float*)carve((size_t)FCMAX*128*4);
  w.x1l=(float*)carve((size_t)FLMAX*128*4);
  w.xl2e=(float*)carve((size_t)N2MAX*128*4);

  void* args[] = { (void*)&in, (void*)&eg, (void*)&w, (void*)&qptr, (void*)&outp };
  hipLaunchCooperativeKernel(mega, dim3(NBLK), dim3(NTHR), args, 0, stream);
}

// Round 3
// 387.805 us; speedup vs baseline: 1.5859x; 1.5859x over previous
//
#include <hip/hip_runtime.h>
#include <math.h>

// R9: resubmit of R8 (infra failure last round) with k4 rebalanced to 512
// threads (1024 + __launch_bounds__ pinned VGPRs to 64 -> spill risk).
// Chain: memset(64B) -> k1 (L2 scan) -> k2 (dedup + dst projections || L1
// scan) -> k3 (per-edge src proj + logit) -> k4 (agg + layer2 + classifier).
#define FAMAX 64     // dst-frontier assets (expected ~11)
#define FCMAX 32     // dst-frontier creators (expected ~1)
#define FLMAX 32     // dst-frontier licensees (expected ~2)
#define N1MAX 512    // layer-1 edges into frontier (expected ~125)
#define N2MAX 128    // layer-2 edges into query (expected ~9)
#define PROJB 128    // k2 blocks reserved for frontier projections
#define SCANB 512    // k2 blocks doing the L1 edge scan

struct Inputs {
  const float *x_asset, *x_creator, *x_licensee;
  const float *Wp_a,*bp_a,*Wp_c,*bp_c,*Wp_l,*bp_l;
  const float *Wl1,*bl1,*Wr1,*br1,*We1,*att1,*bias1;
  const float *Wl2,*bl2,*Wr2,*br2,*We2,*att2,*bias2;
  const float *Wc1,*bc1,*Wc2,*bc2;
};

struct Edges {
  const int *cb_s,*cb_d;  const float* ea_cb;  int Ecb;
  const int *lt_s,*lt_d;  const float* ea_lt;  int Elt;
  const int *sim_s,*sim_d;const float* ea_sim; int Esim;
  const int *fw_s,*fw_d;  const float* ea_fw;  int Efw;
  const int *rcb_s,*rcb_d;const float* ea_rcb; int Ercb;
  const int *rlt_s,*rlt_d;const float* ea_rlt; int Erlt;
};

struct WSP {
  int* cnt;             // [0]=n_l2e [4]=n_l1e  (zeroed by 64B memset)
  int* nf;              // [3] frontier counts (written by k2 block 0)
  int* l2rel; int* l2src; float* l2ea; int* l2slot;
  int* l1rel; int* l1src; int* l1dslot; float* l1ea;
  float* xr1a;          // [FAMAX][4][256]  dst-side xr1 for asset nodes, rels 2..5
  float* xr1c;          // [FCMAX][256]     rel 0
  float* xr1l;          // [FLMAX][256]     rel 1
  float* xl1e;          // [N1MAX][256]
  float* logit1;        // [N1MAX][2]
  float *x1a,*x1c,*x1l; // layer-1 outputs [F*MAX][128]
  float* xl2e;          // [N2MAX][128]
};

__device__ __forceinline__ float leaky(float x){ return x > 0.f ? x : 0.2f*x; }

__device__ __forceinline__ int fsearch(const int* list, int n, int v){
  for (int k=0;k<n;k++) if (list[k]==v) return k;
  return -1;
}

// 128-d projection of `node` of `type` into LDS h0[] using 256 threads.
__device__ __forceinline__ void proj256(int type, int node, const Inputs& in,
                                        float* h0, float* xs, float* part){
  int t = threadIdx.x;
  if (type == 0){
    xs[t]       = in.x_asset[(size_t)node*512 + t];
    xs[t + 256] = in.x_asset[(size_t)node*512 + t + 256];
    __syncthreads();
    int j = t & 127, g2 = t >> 7;
    float acc = 0.f;
    const float* W = in.Wp_a + (size_t)g2*256*128 + j;
    const float* xg = xs + g2*256;
    for (int k=0;k<256;k++) acc = fmaf(xg[k], W[(size_t)k*128], acc);
    part[t] = acc;
    __syncthreads();
    if (t < 128) h0[t] = in.bp_a[t] + part[t] + part[128 + t];
  } else if (type == 1){
    if (t < 128)
      h0[t] = in.bp_c[t] + in.x_creator[node*2]*in.Wp_c[t]
            + in.x_creator[node*2+1]*in.Wp_c[128+t];
  } else {
    if (t < 128)
      h0[t] = in.bp_l[t] + in.x_licensee[node]*in.Wp_l[t];
  }
  __syncthreads();
}

__device__ __forceinline__ void l2hit(int rel, int s, float e, WSP& w){
  int k = atomicAdd(&w.cnt[0], 1);
  if (k < N2MAX){ w.l2rel[k]=rel; w.l2src[k]=s; w.l2ea[k]=e; }
}

__device__ __forceinline__ void l2scan_rel(int rel, const int* sp, const int* dp,
                                           const float* ep, int E, int q,
                                           int gt, int gs, WSP& w){
  int nq = E >> 2;
  const int4* d4 = (const int4*)dp;
  for (int i = gt; i < nq; i += gs){
    int4 d = d4[i];
    int j = i << 2;
    if (d.x == q) l2hit(rel, sp[j],   ep[j],   w);
    if (d.y == q) l2hit(rel, sp[j+1], ep[j+1], w);
    if (d.z == q) l2hit(rel, sp[j+2], ep[j+2], w);
    if (d.w == q) l2hit(rel, sp[j+3], ep[j+3], w);
  }
  int base = nq << 2, tail = E - base;
  if (gt < tail){
    int j = base + gt;
    if (dp[j] == q) l2hit(rel, sp[j], ep[j], w);
  }
}

__device__ __forceinline__ void l1hit(int rel, int s, int slot, float e, WSP& w){
  int k = atomicAdd(&w.cnt[4], 1);
  if (k < N1MAX){ w.l1rel[k]=rel; w.l1src[k]=s; w.l1dslot[k]=slot; w.l1ea[k]=e; }
}

__device__ __forceinline__ void l1scan_rel(int rel, const int* sp, const int* dp,
                                           const float* ep, int E,
                                           const int* flist, int fn,
                                           int gt, int gs, WSP& w){
  int nq = E >> 2;
  const int4* d4 = (const int4*)dp;
  for (int i = gt; i < nq; i += gs){
    int4 d = d4[i];
    int j = i << 2;
    int s0 = fsearch(flist, fn, d.x); if (s0>=0) l1hit(rel, sp[j],   s0, ep[j],   w);
    int s1 = fsearch(flist, fn, d.y); if (s1>=0) l1hit(rel, sp[j+1], s1, ep[j+1], w);
    int s2 = fsearch(flist, fn, d.z); if (s2>=0) l1hit(rel, sp[j+2], s2, ep[j+2], w);
    int s3 = fsearch(flist, fn, d.w); if (s3>=0) l1hit(rel, sp[j+3], s3, ep[j+3], w);
  }
  int base = nq << 2, tail = E - base;
  if (gt < tail){
    int j = base + gt;
    int s0 = fsearch(flist, fn, dp[j]);
    if (s0>=0) l1hit(rel, sp[j], s0, ep[j], w);
  }
}

// K1: scan Asset-targeting relations for dst == q -> L2 edge list.
__global__ void __launch_bounds__(256) k1(Edges eg, const int* qptr, WSP w){
  int q = qptr[0];
  int gt = blockIdx.x*256 + threadIdx.x, gs = gridDim.x*256;
  l2scan_rel(2, eg.sim_s, eg.sim_d, eg.ea_sim, eg.Esim, q, gt, gs, w);
  l2scan_rel(3, eg.fw_s,  eg.fw_d,  eg.ea_fw,  eg.Efw,  q, gt, gs, w);
  l2scan_rel(4, eg.rcb_s, eg.rcb_d, eg.ea_rcb, eg.Ercb, q, gt, gs, w);
  l2scan_rel(5, eg.rlt_s, eg.rlt_d, eg.ea_rlt, eg.Erlt, q, gt, gs, w);
}

// K2: every block dedups the L2 list into LDS frontier lists (deterministic,
// identical across blocks). Blocks [0,PROJB): project frontier node b and
// precompute its xr1 vectors. Blocks [PROJB, PROJB+SCANB): scan all 6
// relations for dst-in-frontier -> L1 edge list. Both run concurrently.
__global__ void __launch_bounds__(256) k2(Inputs in, Edges eg, WSP w, const int* qptr){
  __shared__ float xs[512], part[256], h0[128];
  __shared__ int s_fa[FAMAX], s_fc[FCMAX], s_fl[FLMAX];
  __shared__ int s_nf[3];
  __shared__ int s_l2rel[N2MAX], s_l2src[N2MAX], s_l2slot[N2MAX];
  int b = blockIdx.x, t = threadIdx.x;
  int q = qptr[0];
  int n2 = min(w.cnt[0], N2MAX);
  for (int i=t; i<n2; i+=256){ s_l2rel[i]=w.l2rel[i]; s_l2src[i]=w.l2src[i]; }
  __syncthreads();
  if (t==0){
    int nfa=0,nfc=0,nfl=0;
    s_fa[nfa++]=q;                      // q is always asset slot 0
    for (int i=0;i<n2;i++){
      int rel=s_l2rel[i], src=s_l2src[i], s=-1;
      if (rel<=3){ s=fsearch(s_fa,nfa,src); if (s<0 && nfa<FAMAX){ s=nfa; s_fa[nfa++]=src; } }
      else if (rel==4){ s=fsearch(s_fc,nfc,src); if (s<0 && nfc<FCMAX){ s=nfc; s_fc[nfc++]=src; } }
      else { s=fsearch(s_fl,nfl,src); if (s<0 && nfl<FLMAX){ s=nfl; s_fl[nfl++]=src; } }
      s_l2slot[i]=s;                    // -1 on frontier-capacity overflow
    }
    s_nf[0]=nfa; s_nf[1]=nfc; s_nf[2]=nfl;
    if (b==0){
      w.nf[0]=nfa; w.nf[1]=nfc; w.nf[2]=nfl;
      for (int i=0;i<n2;i++) w.l2slot[i]=s_l2slot[i];
    }
  }
  __syncthreads();
  int nfa=s_nf[0], nfc=s_nf[1], nfl=s_nf[2];
  if (b < PROJB){
    int nf = nfa+nfc+nfl;
    if (b < nf){
      int type, slot, node;
      if (b<nfa){ type=0; slot=b; node=s_fa[slot]; }
      else if (b<nfa+nfc){ type=1; slot=b-nfa; node=s_fc[slot]; }
      else { type=2; slot=b-nfa-nfc; node=s_fl[slot]; }
      proj256(type, node, in, h0, xs, part);
      if (type==0){
        for (int rr=0; rr<4; rr++){
          int r = 2+rr;
          float acc = in.br1[r*256+t];
          const float* W = in.Wr1 + (size_t)r*128*256 + t;
          for (int c=0;c<128;c++) acc = fmaf(h0[c], W[(size_t)c*256], acc);
          w.xr1a[((size_t)slot*4+rr)*256 + t] = acc;
        }
      } else if (type==1){
        float acc = in.br1[t];
        const float* W = in.Wr1 + t;
        for (int c=0;c<128;c++) acc = fmaf(h0[c], W[(size_t)c*256], acc);
        w.xr1c[(size_t)slot*256+t] = acc;
      } else {
        float acc = in.br1[256+t];
        const float* W = in.Wr1 + (size_t)128*256 + t;
        for (int c=0;c<128;c++) acc = fmaf(h0[c], W[(size_t)c*256], acc);
        w.xr1l[(size_t)slot*256+t] = acc;
      }
    }
    return;
  }
  int gt = (b-PROJB)*256 + t, gs = SCANB*256;
  l1scan_rel(0, eg.cb_s,  eg.cb_d,  eg.ea_cb,  eg.Ecb,  s_fc, nfc, gt, gs, w);
  l1scan_rel(1, eg.lt_s,  eg.lt_d,  eg.ea_lt,  eg.Elt,  s_fl, nfl, gt, gs, w);
  l1scan_rel(2, eg.sim_s, eg.sim_d, eg.ea_sim, eg.Esim, s_fa, nfa, gt, gs, w);
  l1scan_rel(3, eg.fw_s,  eg.fw_d,  eg.ea_fw,  eg.Efw,  s_fa, nfa, gt, gs, w);
  l1scan_rel(4, eg.rcb_s, eg.rcb_d, eg.ea_rcb, eg.Ercb, s_fa, nfa, gt, gs, w);
  l1scan_rel(5, eg.rlt_s, eg.rlt_d, eg.ea_rlt, eg.Erlt, s_fa, nfa, gt, gs, w);
}

// K3: per L1 edge (256 threads): proj(src) -> xl1 (stored), read precomputed
// xr1, attention logits via wave shuffle reduce.
__global__ void __launch_bounds__(256) k3(Inputs in, WSP w){
  __shared__ float xs[512], part[256], h0[128];
  __shared__ float pr[4];
  int t = threadIdx.x;
  int n1 = min(w.cnt[4], N1MAX);
  for (int e = blockIdx.x; e < n1; e += gridDim.x){
    int rel = w.l1rel[e], src = w.l1src[e], dslot = w.l1dslot[e];
    float ea = w.l1ea[e];
    int stype = (rel<=3)?0:(rel==4?1:2);
    proj256(stype, src, in, h0, xs, part);
    float xl1 = in.bl1[rel*256+t];
    {
      const float* W = in.Wl1 + (size_t)rel*128*256 + t;
      for (int c=0;c<128;c++) xl1 = fmaf(h0[c], W[(size_t)c*256], xl1);
    }
    w.xl1e[(size_t)e*256+t] = xl1;
    float xr1 = (rel==0) ? w.xr1c[(size_t)dslot*256+t]
              : (rel==1) ? w.xr1l[(size_t)dslot*256+t]
              : w.xr1a[((size_t)dslot*4 + (rel-2))*256 + t];
    float ev = leaky(xl1 + xr1 + ea*in.We1[rel*256+t]);
    float rd = ev * in.att1[(rel*2 + (t>>7))*128 + (t&127)];
    for (int off=32; off; off>>=1) rd += __shfl_down(rd, off);
    if ((t&63)==0) pr[t>>6] = rd;
    __syncthreads();
    if (t==0){ w.logit1[2*e]=pr[0]+pr[1]; w.logit1[2*e+1]=pr[2]+pr[3]; }
    __syncthreads();
  }
}

// K4: one 512-thread block. Phase A: 4 groups of 128 do per-frontier-node
// segment softmax + aggregate (keys/logits in LDS). Phase B: 2 groups of 256
// do layer-2 edges (2 per pass), then softmax + classifier head.
__global__ void __launch_bounds__(512) k4(Inputs in, WSP w, float* outp){
  __shared__ int   s_key[N1MAX];
  __shared__ float s_lg0[N1MAX], s_lg1[N1MAX];
  __shared__ int   s2_rel[N2MAX], s2_slot[N2MAX];
  __shared__ float s2_ea[N2MAX], s_lgt2[N2MAX];
  __shared__ float s_xq[128], s_xr2[4*128];
  __shared__ float sg_h[2][128], sg_part[2][256], sg_pr[2][2];
  __shared__ float s_x2[128], s_hid[128];
  int t = threadIdx.x;
  int n1 = min(w.cnt[4], N1MAX);
  int n2 = min(w.cnt[0], N2MAX);
  int nfa = w.nf[0], nfc = w.nf[1], nfl = w.nf[2];
  int nf = nfa+nfc+nfl;
  for (int i=t; i<n1; i+=512){
    s_key[i] = (w.l1rel[i]<<8) | w.l1dslot[i];
    s_lg0[i] = w.logit1[2*i];
    s_lg1[i] = w.logit1[2*i+1];
  }
  for (int i=t; i<n2; i+=512){
    s2_rel[i]=w.l2rel[i]; s2_slot[i]=w.l2slot[i]; s2_ea[i]=w.l2ea[i];
  }
  __syncthreads();
  // ---- Phase A: layer-1 aggregation, 4 groups of 128 ----
  {
    int g = t>>7, lane = t&127;
    for (int fn=g; fn<nf; fn+=4){
      int type, slot;
      if (fn<nfa){ type=0; slot=fn; }
      else if (fn<nfa+nfc){ type=1; slot=fn-nfa; }
      else { type=2; slot=fn-nfa-nfc; }
      int r0,r1;
      if (type==0){ r0=2;r1=5; } else if (type==1){ r0=0;r1=0; } else { r0=1;r1=1; }
      float out=0.f;
      for (int r=r0;r<=r1;r++){
        out += in.bias1[r*128+lane];
        int key=(r<<8)|slot;
        float m0=-INFINITY,m1=-INFINITY;
        for (int i=0;i<n1;i++) if (s_key[i]==key){ m0=fmaxf(m0,s_lg0[i]); m1=fmaxf(m1,s_lg1[i]); }
        if (m0==-INFINITY) continue;
        float d0=0.f,d1=0.f,a0=0.f,a1=0.f;
        for (int i=0;i<n1;i++) if (s_key[i]==key){
          float e0=expf(s_lg0[i]-m0), e1=expf(s_lg1[i]-m1);
          d0+=e0; d1+=e1;
          a0=fmaf(e0, w.xl1e[(size_t)i*256+lane],     a0);
          a1=fmaf(e1, w.xl1e[(size_t)i*256+128+lane], a1);
        }
        out += 0.5f*(a0/(d0+1e-16f)+a1/(d1+1e-16f));
      }
      float v=fmaxf(out,0.f);
      if (type==0) w.x1a[(size_t)slot*128+lane]=v;
      else if (type==1) w.x1c[(size_t)slot*128+lane]=v;
      else w.x1l[(size_t)slot*128+lane]=v;
    }
  }
  __syncthreads();
  // ---- Phase B: layer 2, 2 groups of 256 ----
  int g3 = t>>8, i256 = t&255, j = i256&127, gh = i256>>7;
  if (t<128) s_xq[t] = w.x1a[t];     // x1 of q (asset slot 0)
  __syncthreads();
  // xr2 for rels 2..5: group g3 handles rel 2+g3 and 4+g3 (split-K by 2)
  for (int rr=g3; rr<4; rr+=2){
    const float* W = in.Wr2 + (size_t)(2+rr)*128*128 + j;
    float acc=0.f;
    for (int c=gh*64;c<gh*64+64;c++) acc=fmaf(s_xq[c], W[(size_t)c*128], acc);
    sg_part[g3][gh*128+j]=acc;
    __syncthreads();
    if (i256<128) s_xr2[rr*128+j] = in.br2[(2+rr)*128+j] + sg_part[g3][j] + sg_part[g3][128+j];
    __syncthreads();
  }
  int passes=(n2+1)>>1;
  for (int p=0;p<passes;p++){
    int e=p*2+g3;
    bool act = e<n2;
    int rel  = act ? s2_rel[e]  : 2;
    int slot = act ? s2_slot[e] : -1;
    if (act && i256<128){
      const float* xb = (rel<=3)? w.x1a : (rel==4? w.x1c : w.x1l);
      sg_h[g3][j] = (slot>=0)? xb[(size_t)slot*128+j] : 0.f;
    }
    __syncthreads();
    float acc=0.f;
    if (act){
      const float* W = in.Wl2 + (size_t)rel*128*128 + j;
      for (int c=gh*64;c<gh*64+64;c++) acc=fmaf(sg_h[g3][c], W[(size_t)c*128], acc);
    }
    sg_part[g3][gh*128+j]=acc;
    __syncthreads();
    if (act && i256<128){
      float xl2 = in.bl2[rel*128+j] + sg_part[g3][j] + sg_part[g3][128+j];
      w.xl2e[(size_t)e*128+j]=xl2;
      float ev = leaky(xl2 + s_xr2[(rel-2)*128+j] + s2_ea[e]*in.We2[rel*128+j]);
      float rd = ev * in.att2[rel*128+j];
      for (int off=32;off;off>>=1) rd += __shfl_down(rd,off);
      if ((i256&63)==0) sg_pr[g3][i256>>6]=rd;
    }
    __syncthreads();
    if (act && i256==0) s_lgt2[e] = (slot>=0)? (sg_pr[g3][0]+sg_pr[g3][1]) : -INFINITY;
    __syncthreads();
  }
  // ---- segment softmax + aggregate + relu -> classifier head ----
  if (t<128){
    float o=0.f;
    for (int r=2;r<=5;r++){
      o += in.bias2[r*128+t];
      float m=-INFINITY;
      for (int i=0;i<n2;i++) if (s2_rel[i]==r) m=fmaxf(m,s_lgt2[i]);
      if (m==-INFINITY) continue;
      float d=0.f, acc=0.f;
      for (int i=0;i<n2;i++) if (s2_rel[i]==r){
        float e=expf(s_lgt2[i]-m);
        d+=e;
        acc=fmaf(e, w.xl2e[(size_t)i*128+t], acc);
      }
      o += acc/(d+1e-16f);
    }
    s_x2[t]=fmaxf(o,0.f);
  }
  __syncthreads();
  if (t<128){
    float a=in.bc1[t];
    for (int c=0;c<128;c++) a=fmaf(s_x2[c], in.Wc1[c*128+t], a);
    s_hid[t]=fmaxf(a,0.f);
  }
  __syncthreads();
  if (t<3){
    float r=in.bc2[t];
    for (int c=0;c<128;c++) r=fmaf(s_hid[c], in.Wc2[c*3+t], r);
    outp[t]=r;
  }
}

extern "C" void kernel_launch(void* const* d_in, const int* in_sizes, int n_in,
                              void* d_out, int out_size, void* d_ws, size_t ws_size,
                              hipStream_t stream){
  Inputs in;
  in.x_asset   = (const float*)d_in[0];
  in.x_creator = (const float*)d_in[1];
  in.x_licensee= (const float*)d_in[2];
  Edges eg;
  eg.cb_s =(const int*)d_in[3];  eg.cb_d =(const int*)d_in[4];  eg.ea_cb =(const float*)d_in[5];  eg.Ecb = in_sizes[3];
  eg.lt_s =(const int*)d_in[6];  eg.lt_d =(const int*)d_in[7];  eg.ea_lt =(const float*)d_in[8];  eg.Elt = in_sizes[6];
  eg.sim_s=(const int*)d_in[9];  eg.sim_d=(const int*)d_in[10]; eg.ea_sim=(const float*)d_in[11]; eg.Esim= in_sizes[9];
  eg.fw_s =(const int*)d_in[12]; eg.fw_d =(const int*)d_in[13]; eg.ea_fw =(const float*)d_in[14]; eg.Efw = in_sizes[12];
  eg.rcb_s=(const int*)d_in[15]; eg.rcb_d=(const int*)d_in[16]; eg.ea_rcb=(const float*)d_in[17]; eg.Ercb= in_sizes[15];
  eg.rlt_s=(const int*)d_in[18]; eg.rlt_d=(const int*)d_in[19]; eg.ea_rlt=(const float*)d_in[20]; eg.Erlt= in_sizes[18];
  in.Wp_a=(const float*)d_in[21]; in.bp_a=(const float*)d_in[22];
  in.Wp_c=(const float*)d_in[23]; in.bp_c=(const float*)d_in[24];
  in.Wp_l=(const float*)d_in[25]; in.bp_l=(const float*)d_in[26];
  in.Wl1=(const float*)d_in[27]; in.bl1=(const float*)d_in[28];
  in.Wr1=(const float*)d_in[29]; in.br1=(const float*)d_in[30];
  in.We1=(const float*)d_in[31]; in.att1=(const float*)d_in[32]; in.bias1=(const float*)d_in[33];
  in.Wl2=(const float*)d_in[34]; in.bl2=(const float*)d_in[35];
  in.Wr2=(const float*)d_in[36]; in.br2=(const float*)d_in[37];
  in.We2=(const float*)d_in[38]; in.att2=(const float*)d_in[39]; in.bias2=(const float*)d_in[40];
  in.Wc1=(const float*)d_in[41]; in.bc1=(const float*)d_in[42];
  in.Wc2=(const float*)d_in[43]; in.bc2=(const float*)d_in[44];
  const int* qptr = (const int*)d_in[45];
  float* outp = (float*)d_out;

  char* p = (char*)d_ws;
  auto carve = [&](size_t n)->char*{ char* r = p; p += ((n + 255) & ~(size_t)255); return r; };
  WSP w;
  w.cnt  = (int*)carve(16*4);
  w.nf   = (int*)carve(3*4);
  w.l2rel=(int*)carve(N2MAX*4); w.l2src=(int*)carve(N2MAX*4);
  w.l2ea=(float*)carve(N2MAX*4); w.l2slot=(int*)carve(N2MAX*4);
  w.l1rel=(int*)carve(N1MAX*4); w.l1src=(int*)carve(N1MAX*4);
  w.l1dslot=(int*)carve(N1MAX*4); w.l1ea=(float*)carve(N1MAX*4);
  w.xr1a=(float*)carve((size_t)FAMAX*4*256*4);
  w.xr1c=(float*)carve((size_t)FCMAX*256*4);
  w.xr1l=(float*)carve((size_t)FLMAX*256*4);
  w.xl1e=(float*)carve((size_t)N1MAX*256*4);
  w.logit1=(float*)carve((size_t)N1MAX*2*4);
  w.x1a=(float*)carve((size_t)FAMAX*128*4);
  w.x1c=(float*)carve((size_t)FCMAX*128*4);
  w.x1l=(float*)carve((size_t)FLMAX*128*4);
  w.xl2e=(float*)carve((size_t)N2MAX*128*4);

  hipMemsetAsync(w.cnt, 0, 64, stream);   // only the two atomic counters

  int quad2 = (eg.Esim + eg.Efw + eg.Ercb + eg.Erlt)/4 + 1;
  int b1 = (quad2 + 255)/256; if (b1 > 1024) b1 = 1024;
  k1<<<b1, 256, 0, stream>>>(eg, qptr, w);
  k2<<<PROJB + SCANB, 256, 0, stream>>>(in, eg, w, qptr);
  k3<<<256, 256, 0, stream>>>(in, w);
  k4<<<1, 512, 0, stream>>>(in, w, outp);
}

// Round 4
// 300.218 us; speedup vs baseline: 2.0486x; 1.2917x over previous
//
#include <hip/hip_runtime.h>
#include <math.h>

// R10: k4 rewrite. R9 rocprof: k4 = 140 µs of the ~145 µs chain (k1-k3 < 5 µs
// combined) — latency-bound serial 125-iter LDS loops in Phase A
// (4 rels x 2 loops x 125 x ~120cyc ~= 150 µs, matches measurement).
// Fix: counting-sort L1 edges by (rel,slot) in LDS; segment loops run over
// ~9 matching edges instead of 125. Layer-2 epilogue parallelized per-rel.
// k1/k2/k3 identical to R9.
#define FAMAX 64     // dst-frontier assets (expected ~11)
#define FCMAX 32     // dst-frontier creators (expected ~1)
#define FLMAX 32     // dst-frontier licensees (expected ~2)
#define N1MAX 512    // layer-1 edges into frontier (expected ~125)
#define N2MAX 128    // layer-2 edges into query (expected ~9)
#define PROJB 128    // k2 blocks reserved for frontier projections
#define SCANB 512    // k2 blocks doing the L1 edge scan
#define NKEY  384    // 6 rels x 64 slots

struct Inputs {
  const float *x_asset, *x_creator, *x_licensee;
  const float *Wp_a,*bp_a,*Wp_c,*bp_c,*Wp_l,*bp_l;
  const float *Wl1,*bl1,*Wr1,*br1,*We1,*att1,*bias1;
  const float *Wl2,*bl2,*Wr2,*br2,*We2,*att2,*bias2;
  const float *Wc1,*bc1,*Wc2,*bc2;
};

struct Edges {
  const int *cb_s,*cb_d;  const float* ea_cb;  int Ecb;
  const int *lt_s,*lt_d;  const float* ea_lt;  int Elt;
  const int *sim_s,*sim_d;const float* ea_sim; int Esim;
  const int *fw_s,*fw_d;  const float* ea_fw;  int Efw;
  const int *rcb_s,*rcb_d;const float* ea_rcb; int Ercb;
  const int *rlt_s,*rlt_d;const float* ea_rlt; int Erlt;
};

struct WSP {
  int* cnt;             // [0]=n_l2e [4]=n_l1e  (zeroed by 64B memset)
  int* nf;              // [3] frontier counts (written by k2 block 0)
  int* l2rel; int* l2src; float* l2ea; int* l2slot;
  int* l1rel; int* l1src; int* l1dslot; float* l1ea;
  float* xr1a;          // [FAMAX][4][256]  dst-side xr1 for asset nodes, rels 2..5
  float* xr1c;          // [FCMAX][256]     rel 0
  float* xr1l;          // [FLMAX][256]     rel 1
  float* xl1e;          // [N1MAX][256]
  float* logit1;        // [N1MAX][2]
  float *x1a,*x1c,*x1l; // layer-1 outputs [F*MAX][128]
  float* xl2e;          // [N2MAX][128]
};

__device__ __forceinline__ float leaky(float x){ return x > 0.f ? x : 0.2f*x; }

__device__ __forceinline__ int fsearch(const int* list, int n, int v){
  for (int k=0;k<n;k++) if (list[k]==v) return k;
  return -1;
}

// 128-d projection of `node` of `type` into LDS h0[] using 256 threads.
__device__ __forceinline__ void proj256(int type, int node, const Inputs& in,
                                        float* h0, float* xs, float* part){
  int t = threadIdx.x;
  if (type == 0){
    xs[t]       = in.x_asset[(size_t)node*512 + t];
    xs[t + 256] = in.x_asset[(size_t)node*512 + t + 256];
    __syncthreads();
    int j = t & 127, g2 = t >> 7;
    float acc = 0.f;
    const float* W = in.Wp_a + (size_t)g2*256*128 + j;
    const float* xg = xs + g2*256;
    for (int k=0;k<256;k++) acc = fmaf(xg[k], W[(size_t)k*128], acc);
    part[t] = acc;
    __syncthreads();
    if (t < 128) h0[t] = in.bp_a[t] + part[t] + part[128 + t];
  } else if (type == 1){
    if (t < 128)
      h0[t] = in.bp_c[t] + in.x_creator[node*2]*in.Wp_c[t]
            + in.x_creator[node*2+1]*in.Wp_c[128+t];
  } else {
    if (t < 128)
      h0[t] = in.bp_l[t] + in.x_licensee[node]*in.Wp_l[t];
  }
  __syncthreads();
}

__device__ __forceinline__ void l2hit(int rel, int s, float e, WSP& w){
  int k = atomicAdd(&w.cnt[0], 1);
  if (k < N2MAX){ w.l2rel[k]=rel; w.l2src[k]=s; w.l2ea[k]=e; }
}

__device__ __forceinline__ void l2scan_rel(int rel, const int* sp, const int* dp,
                                           const float* ep, int E, int q,
                                           int gt, int gs, WSP& w){
  int nq = E >> 2;
  const int4* d4 = (const int4*)dp;
  for (int i = gt; i < nq; i += gs){
    int4 d = d4[i];
    int j = i << 2;
    if (d.x == q) l2hit(rel, sp[j],   ep[j],   w);
    if (d.y == q) l2hit(rel, sp[j+1], ep[j+1], w);
    if (d.z == q) l2hit(rel, sp[j+2], ep[j+2], w);
    if (d.w == q) l2hit(rel, sp[j+3], ep[j+3], w);
  }
  int base = nq << 2, tail = E - base;
  if (gt < tail){
    int j = base + gt;
    if (dp[j] == q) l2hit(rel, sp[j], ep[j], w);
  }
}

__device__ __forceinline__ void l1hit(int rel, int s, int slot, float e, WSP& w){
  int k = atomicAdd(&w.cnt[4], 1);
  if (k < N1MAX){ w.l1rel[k]=rel; w.l1src[k]=s; w.l1dslot[k]=slot; w.l1ea[k]=e; }
}

__device__ __forceinline__ void l1scan_rel(int rel, const int* sp, const int* dp,
                                           const float* ep, int E,
                                           const int* flist, int fn,
                                           int gt, int gs, WSP& w){
  int nq = E >> 2;
  const int4* d4 = (const int4*)dp;
  for (int i = gt; i < nq; i += gs){
    int4 d = d4[i];
    int j = i << 2;
    int s0 = fsearch(flist, fn, d.x); if (s0>=0) l1hit(rel, sp[j],   s0, ep[j],   w);
    int s1 = fsearch(flist, fn, d.y); if (s1>=0) l1hit(rel, sp[j+1], s1, ep[j+1], w);
    int s2 = fsearch(flist, fn, d.z); if (s2>=0) l1hit(rel, sp[j+2], s2, ep[j+2], w);
    int s3 = fsearch(flist, fn, d.w); if (s3>=0) l1hit(rel, sp[j+3], s3, ep[j+3], w);
  }
  int base = nq << 2, tail = E - base;
  if (gt < tail){
    int j = base + gt;
    int s0 = fsearch(flist, fn, dp[j]);
    if (s0>=0) l1hit(rel, sp[j], s0, ep[j], w);
  }
}

// K1: scan Asset-targeting relations for dst == q -> L2 edge list.
__global__ void __launch_bounds__(256) k1(Edges eg, const int* qptr, WSP w){
  int q = qptr[0];
  int gt = blockIdx.x*256 + threadIdx.x, gs = gridDim.x*256;
  l2scan_rel(2, eg.sim_s, eg.sim_d, eg.ea_sim, eg.Esim, q, gt, gs, w);
  l2scan_rel(3, eg.fw_s,  eg.fw_d,  eg.ea_fw,  eg.Efw,  q, gt, gs, w);
  l2scan_rel(4, eg.rcb_s, eg.rcb_d, eg.ea_rcb, eg.Ercb, q, gt, gs, w);
  l2scan_rel(5, eg.rlt_s, eg.rlt_d, eg.ea_rlt, eg.Erlt, q, gt, gs, w);
}

// K2: every block dedups the L2 list into LDS frontier lists (deterministic,
// identical across blocks). Blocks [0,PROJB): project frontier node b and
// precompute its xr1 vectors. Blocks [PROJB, PROJB+SCANB): scan all 6
// relations for dst-in-frontier -> L1 edge list. Both run concurrently.
__global__ void __launch_bounds__(256) k2(Inputs in, Edges eg, WSP w, const int* qptr){
  __shared__ float xs[512], part[256], h0[128];
  __shared__ int s_fa[FAMAX], s_fc[FCMAX], s_fl[FLMAX];
  __shared__ int s_nf[3];
  __shared__ int s_l2rel[N2MAX], s_l2src[N2MAX], s_l2slot[N2MAX];
  int b = blockIdx.x, t = threadIdx.x;
  int q = qptr[0];
  int n2 = min(w.cnt[0], N2MAX);
  for (int i=t; i<n2; i+=256){ s_l2rel[i]=w.l2rel[i]; s_l2src[i]=w.l2src[i]; }
  __syncthreads();
  if (t==0){
    int nfa=0,nfc=0,nfl=0;
    s_fa[nfa++]=q;                      // q is always asset slot 0
    for (int i=0;i<n2;i++){
      int rel=s_l2rel[i], src=s_l2src[i], s=-1;
      if (rel<=3){ s=fsearch(s_fa,nfa,src); if (s<0 && nfa<FAMAX){ s=nfa; s_fa[nfa++]=src; } }
      else if (rel==4){ s=fsearch(s_fc,nfc,src); if (s<0 && nfc<FCMAX){ s=nfc; s_fc[nfc++]=src; } }
      else { s=fsearch(s_fl,nfl,src); if (s<0 && nfl<FLMAX){ s=nfl; s_fl[nfl++]=src; } }
      s_l2slot[i]=s;                    // -1 on frontier-capacity overflow
    }
    s_nf[0]=nfa; s_nf[1]=nfc; s_nf[2]=nfl;
    if (b==0){
      w.nf[0]=nfa; w.nf[1]=nfc; w.nf[2]=nfl;
      for (int i=0;i<n2;i++) w.l2slot[i]=s_l2slot[i];
    }
  }
  __syncthreads();
  int nfa=s_nf[0], nfc=s_nf[1], nfl=s_nf[2];
  if (b < PROJB){
    int nf = nfa+nfc+nfl;
    if (b < nf){
      int type, slot, node;
      if (b<nfa){ type=0; slot=b; node=s_fa[slot]; }
      else if (b<nfa+nfc){ type=1; slot=b-nfa; node=s_fc[slot]; }
      else { type=2; slot=b-nfa-nfc; node=s_fl[slot]; }
      proj256(type, node, in, h0, xs, part);
      if (type==0){
        for (int rr=0; rr<4; rr++){
          int r = 2+rr;
          float acc = in.br1[r*256+t];
          const float* W = in.Wr1 + (size_t)r*128*256 + t;
          for (int c=0;c<128;c++) acc = fmaf(h0[c], W[(size_t)c*256], acc);
          w.xr1a[((size_t)slot*4+rr)*256 + t] = acc;
        }
      } else if (type==1){
        float acc = in.br1[t];
        const float* W = in.Wr1 + t;
        for (int c=0;c<128;c++) acc = fmaf(h0[c], W[(size_t)c*256], acc);
        w.xr1c[(size_t)slot*256+t] = acc;
      } else {
        float acc = in.br1[256+t];
        const float* W = in.Wr1 + (size_t)128*256 + t;
        for (int c=0;c<128;c++) acc = fmaf(h0[c], W[(size_t)c*256], acc);
        w.xr1l[(size_t)slot*256+t] = acc;
      }
    }
    return;
  }
  int gt = (b-PROJB)*256 + t, gs = SCANB*256;
  l1scan_rel(0, eg.cb_s,  eg.cb_d,  eg.ea_cb,  eg.Ecb,  s_fc, nfc, gt, gs, w);
  l1scan_rel(1, eg.lt_s,  eg.lt_d,  eg.ea_lt,  eg.Elt,  s_fl, nfl, gt, gs, w);
  l1scan_rel(2, eg.sim_s, eg.sim_d, eg.ea_sim, eg.Esim, s_fa, nfa, gt, gs, w);
  l1scan_rel(3, eg.fw_s,  eg.fw_d,  eg.ea_fw,  eg.Efw,  s_fa, nfa, gt, gs, w);
  l1scan_rel(4, eg.rcb_s, eg.rcb_d, eg.ea_rcb, eg.Ercb, s_fa, nfa, gt, gs, w);
  l1scan_rel(5, eg.rlt_s, eg.rlt_d, eg.ea_rlt, eg.Erlt, s_fa, nfa, gt, gs, w);
}

// K3: per L1 edge (256 threads): proj(src) -> xl1 (stored), read precomputed
// xr1, attention logits via wave shuffle reduce.
__global__ void __launch_bounds__(256) k3(Inputs in, WSP w){
  __shared__ float xs[512], part[256], h0[128];
  __shared__ float pr[4];
  int t = threadIdx.x;
  int n1 = min(w.cnt[4], N1MAX);
  for (int e = blockIdx.x; e < n1; e += gridDim.x){
    int rel = w.l1rel[e], src = w.l1src[e], dslot = w.l1dslot[e];
    float ea = w.l1ea[e];
    int stype = (rel<=3)?0:(rel==4?1:2);
    proj256(stype, src, in, h0, xs, part);
    float xl1 = in.bl1[rel*256+t];
    {
      const float* W = in.Wl1 + (size_t)rel*128*256 + t;
      for (int c=0;c<128;c++) xl1 = fmaf(h0[c], W[(size_t)c*256], xl1);
    }
    w.xl1e[(size_t)e*256+t] = xl1;
    float xr1 = (rel==0) ? w.xr1c[(size_t)dslot*256+t]
              : (rel==1) ? w.xr1l[(size_t)dslot*256+t]
              : w.xr1a[((size_t)dslot*4 + (rel-2))*256 + t];
    float ev = leaky(xl1 + xr1 + ea*in.We1[rel*256+t]);
    float rd = ev * in.att1[(rel*2 + (t>>7))*128 + (t&127)];
    for (int off=32; off; off>>=1) rd += __shfl_down(rd, off);
    if ((t&63)==0) pr[t>>6] = rd;
    __syncthreads();
    if (t==0){ w.logit1[2*e]=pr[0]+pr[1]; w.logit1[2*e+1]=pr[2]+pr[3]; }
    __syncthreads();
  }
}

// K4: one 512-thread block.
// Preamble: counting-sort L1 edges by key=(rel*64+slot) in LDS (histogram ->
//   Hillis-Steele scan over 384 keys -> scatter). Segment loops then touch
//   only the ~9 matching edges instead of scanning all ~125.
// Phase A: 4 groups of 128, one frontier node per group per pass.
// Phase B: xr2 one-rel-per-group; edge loop 4 edges/pass; final softmax
//   one-rel-per-group; classifier head.
__global__ void __launch_bounds__(512) k4(Inputs in, WSP w, float* outp){
  __shared__ int   s_ekey[N1MAX], s_sorted[N1MAX];
  __shared__ float s_lg0[N1MAX], s_lg1[N1MAX];
  __shared__ int   s_cnt[NKEY], s_scan[NKEY];
  __shared__ int   s2_rel[N2MAX], s2_slot[N2MAX];
  __shared__ float s2_ea[N2MAX], s_lgt2[N2MAX];
  __shared__ float s_xq[128], s_xr2[4*128];
  __shared__ float sg_h[4][128], sg_pr[4][2];
  __shared__ float s_part4[4][128];
  __shared__ float s_x2[128], s_hid[128];
  int t = threadIdx.x;
  int n1 = min(w.cnt[4], N1MAX);
  int n2 = min(w.cnt[0], N2MAX);
  int nfa = w.nf[0], nfc = w.nf[1], nfl = w.nf[2];
  int nf = nfa+nfc+nfl;
  // ---- preamble: load + histogram ----
  for (int i=t; i<NKEY; i+=512) s_cnt[i]=0;
  __syncthreads();
  for (int i=t; i<n1; i+=512){
    int key = w.l1rel[i]*64 + w.l1dslot[i];
    s_ekey[i]=key;
    s_lg0[i]=w.logit1[2*i];
    s_lg1[i]=w.logit1[2*i+1];
    atomicAdd(&s_cnt[key],1);
  }
  for (int i=t; i<n2; i+=512){
    s2_rel[i]=w.l2rel[i]; s2_slot[i]=w.l2slot[i]; s2_ea[i]=w.l2ea[i];
  }
  __syncthreads();
  // inclusive scan of s_cnt -> s_scan (Hillis-Steele, 384 keys)
  if (t<NKEY) s_scan[t]=s_cnt[t];
  __syncthreads();
  for (int d=1; d<NKEY; d<<=1){
    int v=0;
    if (t<NKEY && t>=d) v=s_scan[t-d];
    __syncthreads();
    if (t<NKEY) s_scan[t]+=v;
    __syncthreads();
  }
  // scatter using a cursor initialized to the exclusive offset
  __shared__ int s_cur[NKEY];
  if (t<NKEY) s_cur[t]=s_scan[t]-s_cnt[t];
  __syncthreads();
  for (int i=t; i<n1; i+=512){
    int pos = atomicAdd(&s_cur[s_ekey[i]],1);
    s_sorted[pos]=i;
  }
  __syncthreads();
  // ---- Phase A: layer-1 segment softmax + aggregate, 4 groups of 128 ----
  {
    int g = t>>7, lane = t&127;
    for (int fn=g; fn<nf; fn+=4){
      int type, slot;
      if (fn<nfa){ type=0; slot=fn; }
      else if (fn<nfa+nfc){ type=1; slot=fn-nfa; }
      else { type=2; slot=fn-nfa-nfc; }
      int r0,r1;
      if (type==0){ r0=2;r1=5; } else if (type==1){ r0=0;r1=0; } else { r0=1;r1=1; }
      float out=0.f;
      for (int r=r0;r<=r1;r++){
        out += in.bias1[r*128+lane];
        int key=r*64+slot;
        int c=s_cnt[key];
        if (c==0) continue;
        int beg=s_scan[key]-c;
        float m0=-INFINITY,m1=-INFINITY;
        for (int o=0;o<c;o++){
          int i=s_sorted[beg+o];
          m0=fmaxf(m0,s_lg0[i]); m1=fmaxf(m1,s_lg1[i]);
        }
        float d0=0.f,d1=0.f,a0=0.f,a1=0.f;
        for (int o=0;o<c;o++){
          int i=s_sorted[beg+o];
          float e0=expf(s_lg0[i]-m0), e1=expf(s_lg1[i]-m1);
          d0+=e0; d1+=e1;
          a0=fmaf(e0, w.xl1e[(size_t)i*256+lane],     a0);
          a1=fmaf(e1, w.xl1e[(size_t)i*256+128+lane], a1);
        }
        out += 0.5f*(a0/(d0+1e-16f)+a1/(d1+1e-16f));
      }
      float v=fmaxf(out,0.f);
      if (type==0) w.x1a[(size_t)slot*128+lane]=v;
      else if (type==1) w.x1c[(size_t)slot*128+lane]=v;
      else w.x1l[(size_t)slot*128+lane]=v;
    }
  }
  __syncthreads();
  // ---- Phase B: layer 2, 4 groups of 128 ----
  int g = t>>7, lane = t&127;
  if (t<128) s_xq[t] = w.x1a[t];     // x1 of q (asset slot 0)
  __syncthreads();
  {  // xr2: group g handles rel 2+g
    int r=2+g;
    const float* W = in.Wr2 + (size_t)r*128*128 + lane;
    float acc = in.br2[r*128+lane];
    for (int c=0;c<128;c++) acc=fmaf(s_xq[c], W[(size_t)c*128], acc);
    s_xr2[g*128+lane]=acc;
  }
  __syncthreads();
  int passes=(n2+3)>>2;
  for (int p=0;p<passes;p++){
    int e=p*4+g;
    bool act = e<n2;
    int rel  = act ? s2_rel[e]  : 2;
    int slot = act ? s2_slot[e] : -1;
    if (act){
      const float* xb = (rel<=3)? w.x1a : (rel==4? w.x1c : w.x1l);
      sg_h[g][lane] = (slot>=0)? xb[(size_t)slot*128+lane] : 0.f;
    }
    __syncthreads();
    if (act){
      const float* W = in.Wl2 + (size_t)rel*128*128 + lane;
      float xl2 = in.bl2[rel*128+lane];
      for (int c=0;c<128;c++) xl2=fmaf(sg_h[g][c], W[(size_t)c*128], xl2);
      w.xl2e[(size_t)e*128+lane]=xl2;
      float ev = leaky(xl2 + s_xr2[(rel-2)*128+lane] + s2_ea[e]*in.We2[rel*128+lane]);
      float rd = ev * in.att2[rel*128+lane];
      for (int off=32;off;off>>=1) rd += __shfl_down(rd,off);
      if ((lane&63)==0) sg_pr[g][lane>>6]=rd;
    }
    __syncthreads();
    if (act && lane==0) s_lgt2[e] = (slot>=0)? (sg_pr[g][0]+sg_pr[g][1]) : -INFINITY;
    __syncthreads();
  }
  // ---- layer-2 segment softmax: one rel per group ----
  {
    int r=2+g;
    float o = in.bias2[r*128+lane];
    float m=-INFINITY;
    for (int i=0;i<n2;i++) if (s2_rel[i]==r) m=fmaxf(m,s_lgt2[i]);
    if (m!=-INFINITY){
      float d=0.f, acc=0.f;
      for (int i=0;i<n2;i++) if (s2_rel[i]==r){
        float e=expf(s_lgt2[i]-m);
        d+=e;
        acc=fmaf(e, w.xl2e[(size_t)i*128+lane], acc);
      }
      o += acc/(d+1e-16f);
    }
    s_part4[g][lane]=o;
  }
  __syncthreads();
  if (t<128) s_x2[t]=fmaxf(s_part4[0][t]+s_part4[1][t]+s_part4[2][t]+s_part4[3][t], 0.f);
  __syncthreads();
  if (t<128){
    float a=in.bc1[t];
    for (int c=0;c<128;c++) a=fmaf(s_x2[c], in.Wc1[c*128+t], a);
    s_hid[t]=fmaxf(a,0.f);
  }
  __syncthreads();
  if (t<3){
    float r=in.bc2[t];
    for (int c=0;c<128;c++) r=fmaf(s_hid[c], in.Wc2[c*3+t], r);
    outp[t]=r;
  }
}

extern "C" void kernel_launch(void* const* d_in, const int* in_sizes, int n_in,
                              void* d_out, int out_size, void* d_ws, size_t ws_size,
                              hipStream_t stream){
  Inputs in;
  in.x_asset   = (const float*)d_in[0];
  in.x_creator = (const float*)d_in[1];
  in.x_licensee= (const float*)d_in[2];
  Edges eg;
  eg.cb_s =(const int*)d_in[3];  eg.cb_d =(const int*)d_in[4];  eg.ea_cb =(const float*)d_in[5];  eg.Ecb = in_sizes[3];
  eg.lt_s =(const int*)d_in[6];  eg.lt_d =(const int*)d_in[7];  eg.ea_lt =(const float*)d_in[8];  eg.Elt = in_sizes[6];
  eg.sim_s=(const int*)d_in[9];  eg.sim_d=(const int*)d_in[10]; eg.ea_sim=(const float*)d_in[11]; eg.Esim= in_sizes[9];
  eg.fw_s =(const int*)d_in[12]; eg.fw_d =(const int*)d_in[13]; eg.ea_fw =(const float*)d_in[14]; eg.Efw = in_sizes[12];
  eg.rcb_s=(const int*)d_in[15]; eg.rcb_d=(const int*)d_in[16]; eg.ea_rcb=(const float*)d_in[17]; eg.Ercb= in_sizes[15];
  eg.rlt_s=(const int*)d_in[18]; eg.rlt_d=(const int*)d_in[19]; eg.ea_rlt=(const float*)d_in[20]; eg.Erlt= in_sizes[18];
  in.Wp_a=(const float*)d_in[21]; in.bp_a=(const float*)d_in[22];
  in.Wp_c=(const float*)d_in[23]; in.bp_c=(const float*)d_in[24];
  in.Wp_l=(const float*)d_in[25]; in.bp_l=(const float*)d_in[26];
  in.Wl1=(const float*)d_in[27]; in.bl1=(const float*)d_in[28];
  in.Wr1=(const float*)d_in[29]; in.br1=(const float*)d_in[30];
  in.We1=(const float*)d_in[31]; in.att1=(const float*)d_in[32]; in.bias1=(const float*)d_in[33];
  in.Wl2=(const float*)d_in[34]; in.bl2=(const float*)d_in[35];
  in.Wr2=(const float*)d_in[36]; in.br2=(const float*)d_in[37];
  in.We2=(const float*)d_in[38]; in.att2=(const float*)d_in[39]; in.bias2=(const float*)d_in[40];
  in.Wc1=(const float*)d_in[41]; in.bc1=(const float*)d_in[42];
  in.Wc2=(const float*)d_in[43]; in.bc2=(const float*)d_in[44];
  const int* qptr = (const int*)d_in[45];
  float* outp = (float*)d_out;

  char* p = (char*)d_ws;
  auto carve = [&](size_t n)->char*{ char* r = p; p += ((n + 255) & ~(size_t)255); return r; };
  WSP w;
  w.cnt  = (int*)carve(16*4);
  w.nf   = (int*)carve(3*4);
  w.l2rel=(int*)carve(N2MAX*4); w.l2src=(int*)carve(N2MAX*4);
  w.l2ea=(float*)carve(N2MAX*4); w.l2slot=(int*)carve(N2MAX*4);
  w.l1rel=(int*)carve(N1MAX*4); w.l1src=(int*)carve(N1MAX*4);
  w.l1dslot=(int*)carve(N1MAX*4); w.l1ea=(float*)carve(N1MAX*4);
  w.xr1a=(float*)carve((size_t)FAMAX*4*256*4);
  w.xr1c=(float*)carve((size_t)FCMAX*256*4);
  w.xr1l=(float*)carve((size_t)FLMAX*256*4);
  w.xl1e=(float*)carve((size_t)N1MAX*256*4);
  w.logit1=(float*)carve((size_t)N1MAX*2*4);
  w.x1a=(float*)carve((size_t)FAMAX*128*4);
  w.x1c=(float*)carve((size_t)FCMAX*128*4);
  w.x1l=(float*)carve((size_t)FLMAX*128*4);
  w.xl2e=(float*)carve((size_t)N2MAX*128*4);

  hipMemsetAsync(w.cnt, 0, 64, stream);   // only the two atomic counters

  int quad2 = (eg.Esim + eg.Efw + eg.Ercb + eg.Erlt)/4 + 1;
  int b1 = (quad2 + 255)/256; if (b1 > 1024) b1 = 1024;
  k1<<<b1, 256, 0, stream>>>(eg, qptr, w);
  k2<<<PROJB + SCANB, 256, 0, stream>>>(in, eg, w, qptr);
  k3<<<256, 256, 0, stream>>>(in, w);
  k4<<<1, 512, 0, stream>>>(in, w, outp);
}

// Round 5
// 294.750 us; speedup vs baseline: 2.0866x; 1.0186x over previous
//
#include <hip/hip_runtime.h>
#include <math.h>

// R11: split R10's single-block k4 (measured ~52 µs: one CU serializing
// Phase A + ~600 KB cold-weight streaming) into three parallel stages:
//   k4a: per-frontier-node blocks (parallel filter + segment softmax-agg)
//   k4b: per-L2-edge blocks (inline xr2 + xl2 GEMVs, logit)
//   k4c: single small block (layer-2 softmax + classifier)
// k1/k2/k3 identical to R9/R10 (measured sum < 6 µs).
#define FAMAX 64     // dst-frontier assets (expected ~11)
#define FCMAX 32     // dst-frontier creators (expected ~1)
#define FLMAX 32     // dst-frontier licensees (expected ~2)
#define N1MAX 512    // layer-1 edges into frontier (expected ~125)
#define N2MAX 128    // layer-2 edges into query (expected ~9)
#define PROJB 128    // k2 blocks reserved for frontier projections
#define SCANB 512    // k2 blocks doing the L1 edge scan

struct Inputs {
  const float *x_asset, *x_creator, *x_licensee;
  const float *Wp_a,*bp_a,*Wp_c,*bp_c,*Wp_l,*bp_l;
  const float *Wl1,*bl1,*Wr1,*br1,*We1,*att1,*bias1;
  const float *Wl2,*bl2,*Wr2,*br2,*We2,*att2,*bias2;
  const float *Wc1,*bc1,*Wc2,*bc2;
};

struct Edges {
  const int *cb_s,*cb_d;  const float* ea_cb;  int Ecb;
  const int *lt_s,*lt_d;  const float* ea_lt;  int Elt;
  const int *sim_s,*sim_d;const float* ea_sim; int Esim;
  const int *fw_s,*fw_d;  const float* ea_fw;  int Efw;
  const int *rcb_s,*rcb_d;const float* ea_rcb; int Ercb;
  const int *rlt_s,*rlt_d;const float* ea_rlt; int Erlt;
};

struct WSP {
  int* cnt;             // [0]=n_l2e [4]=n_l1e  (zeroed by 64B memset)
  int* nf;              // [3] frontier counts (written by k2 block 0)
  int* l2rel; int* l2src; float* l2ea; int* l2slot;
  int* l1rel; int* l1src; int* l1dslot; float* l1ea;
  float* xr1a;          // [FAMAX][4][256]  dst-side xr1 for asset nodes, rels 2..5
  float* xr1c;          // [FCMAX][256]     rel 0
  float* xr1l;          // [FLMAX][256]     rel 1
  float* xl1e;          // [N1MAX][256]
  float* logit1;        // [N1MAX][2]
  float *x1a,*x1c,*x1l; // layer-1 outputs [F*MAX][128]
  float* xl2e;          // [N2MAX][128]
  float* logit2;        // [N2MAX]
};

__device__ __forceinline__ float leaky(float x){ return x > 0.f ? x : 0.2f*x; }

__device__ __forceinline__ int fsearch(const int* list, int n, int v){
  for (int k=0;k<n;k++) if (list[k]==v) return k;
  return -1;
}

// 128-d projection of `node` of `type` into LDS h0[] using 256 threads.
__device__ __forceinline__ void proj256(int type, int node, const Inputs& in,
                                        float* h0, float* xs, float* part){
  int t = threadIdx.x;
  if (type == 0){
    xs[t]       = in.x_asset[(size_t)node*512 + t];
    xs[t + 256] = in.x_asset[(size_t)node*512 + t + 256];
    __syncthreads();
    int j = t & 127, g2 = t >> 7;
    float acc = 0.f;
    const float* W = in.Wp_a + (size_t)g2*256*128 + j;
    const float* xg = xs + g2*256;
    for (int k=0;k<256;k++) acc = fmaf(xg[k], W[(size_t)k*128], acc);
    part[t] = acc;
    __syncthreads();
    if (t < 128) h0[t] = in.bp_a[t] + part[t] + part[128 + t];
  } else if (type == 1){
    if (t < 128)
      h0[t] = in.bp_c[t] + in.x_creator[node*2]*in.Wp_c[t]
            + in.x_creator[node*2+1]*in.Wp_c[128+t];
  } else {
    if (t < 128)
      h0[t] = in.bp_l[t] + in.x_licensee[node]*in.Wp_l[t];
  }
  __syncthreads();
}

__device__ __forceinline__ void l2hit(int rel, int s, float e, WSP& w){
  int k = atomicAdd(&w.cnt[0], 1);
  if (k < N2MAX){ w.l2rel[k]=rel; w.l2src[k]=s; w.l2ea[k]=e; }
}

__device__ __forceinline__ void l2scan_rel(int rel, const int* sp, const int* dp,
                                           const float* ep, int E, int q,
                                           int gt, int gs, WSP& w){
  int nq = E >> 2;
  const int4* d4 = (const int4*)dp;
  for (int i = gt; i < nq; i += gs){
    int4 d = d4[i];
    int j = i << 2;
    if (d.x == q) l2hit(rel, sp[j],   ep[j],   w);
    if (d.y == q) l2hit(rel, sp[j+1], ep[j+1], w);
    if (d.z == q) l2hit(rel, sp[j+2], ep[j+2], w);
    if (d.w == q) l2hit(rel, sp[j+3], ep[j+3], w);
  }
  int base = nq << 2, tail = E - base;
  if (gt < tail){
    int j = base + gt;
    if (dp[j] == q) l2hit(rel, sp[j], ep[j], w);
  }
}

__device__ __forceinline__ void l1hit(int rel, int s, int slot, float e, WSP& w){
  int k = atomicAdd(&w.cnt[4], 1);
  if (k < N1MAX){ w.l1rel[k]=rel; w.l1src[k]=s; w.l1dslot[k]=slot; w.l1ea[k]=e; }
}

__device__ __forceinline__ void l1scan_rel(int rel, const int* sp, const int* dp,
                                           const float* ep, int E,
                                           const int* flist, int fn,
                                           int gt, int gs, WSP& w){
  int nq = E >> 2;
  const int4* d4 = (const int4*)dp;
  for (int i = gt; i < nq; i += gs){
    int4 d = d4[i];
    int j = i << 2;
    int s0 = fsearch(flist, fn, d.x); if (s0>=0) l1hit(rel, sp[j],   s0, ep[j],   w);
    int s1 = fsearch(flist, fn, d.y); if (s1>=0) l1hit(rel, sp[j+1], s1, ep[j+1], w);
    int s2 = fsearch(flist, fn, d.z); if (s2>=0) l1hit(rel, sp[j+2], s2, ep[j+2], w);
    int s3 = fsearch(flist, fn, d.w); if (s3>=0) l1hit(rel, sp[j+3], s3, ep[j+3], w);
  }
  int base = nq << 2, tail = E - base;
  if (gt < tail){
    int j = base + gt;
    int s0 = fsearch(flist, fn, dp[j]);
    if (s0>=0) l1hit(rel, sp[j], s0, ep[j], w);
  }
}

// K1: scan Asset-targeting relations for dst == q -> L2 edge list.
__global__ void __launch_bounds__(256) k1(Edges eg, const int* qptr, WSP w){
  int q = qptr[0];
  int gt = blockIdx.x*256 + threadIdx.x, gs = gridDim.x*256;
  l2scan_rel(2, eg.sim_s, eg.sim_d, eg.ea_sim, eg.Esim, q, gt, gs, w);
  l2scan_rel(3, eg.fw_s,  eg.fw_d,  eg.ea_fw,  eg.Efw,  q, gt, gs, w);
  l2scan_rel(4, eg.rcb_s, eg.rcb_d, eg.ea_rcb, eg.Ercb, q, gt, gs, w);
  l2scan_rel(5, eg.rlt_s, eg.rlt_d, eg.ea_rlt, eg.Erlt, q, gt, gs, w);
}

// K2: every block dedups the L2 list into LDS frontier lists (deterministic,
// identical across blocks). Blocks [0,PROJB): project frontier node b and
// precompute its xr1 vectors. Blocks [PROJB, PROJB+SCANB): scan all 6
// relations for dst-in-frontier -> L1 edge list. Both run concurrently.
__global__ void __launch_bounds__(256) k2(Inputs in, Edges eg, WSP w, const int* qptr){
  __shared__ float xs[512], part[256], h0[128];
  __shared__ int s_fa[FAMAX], s_fc[FCMAX], s_fl[FLMAX];
  __shared__ int s_nf[3];
  __shared__ int s_l2rel[N2MAX], s_l2src[N2MAX], s_l2slot[N2MAX];
  int b = blockIdx.x, t = threadIdx.x;
  int q = qptr[0];
  int n2 = min(w.cnt[0], N2MAX);
  for (int i=t; i<n2; i+=256){ s_l2rel[i]=w.l2rel[i]; s_l2src[i]=w.l2src[i]; }
  __syncthreads();
  if (t==0){
    int nfa=0,nfc=0,nfl=0;
    s_fa[nfa++]=q;                      // q is always asset slot 0
    for (int i=0;i<n2;i++){
      int rel=s_l2rel[i], src=s_l2src[i], s=-1;
      if (rel<=3){ s=fsearch(s_fa,nfa,src); if (s<0 && nfa<FAMAX){ s=nfa; s_fa[nfa++]=src; } }
      else if (rel==4){ s=fsearch(s_fc,nfc,src); if (s<0 && nfc<FCMAX){ s=nfc; s_fc[nfc++]=src; } }
      else { s=fsearch(s_fl,nfl,src); if (s<0 && nfl<FLMAX){ s=nfl; s_fl[nfl++]=src; } }
      s_l2slot[i]=s;                    // -1 on frontier-capacity overflow
    }
    s_nf[0]=nfa; s_nf[1]=nfc; s_nf[2]=nfl;
    if (b==0){
      w.nf[0]=nfa; w.nf[1]=nfc; w.nf[2]=nfl;
      for (int i=0;i<n2;i++) w.l2slot[i]=s_l2slot[i];
    }
  }
  __syncthreads();
  int nfa=s_nf[0], nfc=s_nf[1], nfl=s_nf[2];
  if (b < PROJB){
    int nf = nfa+nfc+nfl;
    if (b < nf){
      int type, slot, node;
      if (b<nfa){ type=0; slot=b; node=s_fa[slot]; }
      else if (b<nfa+nfc){ type=1; slot=b-nfa; node=s_fc[slot]; }
      else { type=2; slot=b-nfa-nfc; node=s_fl[slot]; }
      proj256(type, node, in, h0, xs, part);
      if (type==0){
        for (int rr=0; rr<4; rr++){
          int r = 2+rr;
          float acc = in.br1[r*256+t];
          const float* W = in.Wr1 + (size_t)r*128*256 + t;
          for (int c=0;c<128;c++) acc = fmaf(h0[c], W[(size_t)c*256], acc);
          w.xr1a[((size_t)slot*4+rr)*256 + t] = acc;
        }
      } else if (type==1){
        float acc = in.br1[t];
        const float* W = in.Wr1 + t;
        for (int c=0;c<128;c++) acc = fmaf(h0[c], W[(size_t)c*256], acc);
        w.xr1c[(size_t)slot*256+t] = acc;
      } else {
        float acc = in.br1[256+t];
        const float* W = in.Wr1 + (size_t)128*256 + t;
        for (int c=0;c<128;c++) acc = fmaf(h0[c], W[(size_t)c*256], acc);
        w.xr1l[(size_t)slot*256+t] = acc;
      }
    }
    return;
  }
  int gt = (b-PROJB)*256 + t, gs = SCANB*256;
  l1scan_rel(0, eg.cb_s,  eg.cb_d,  eg.ea_cb,  eg.Ecb,  s_fc, nfc, gt, gs, w);
  l1scan_rel(1, eg.lt_s,  eg.lt_d,  eg.ea_lt,  eg.Elt,  s_fl, nfl, gt, gs, w);
  l1scan_rel(2, eg.sim_s, eg.sim_d, eg.ea_sim, eg.Esim, s_fa, nfa, gt, gs, w);
  l1scan_rel(3, eg.fw_s,  eg.fw_d,  eg.ea_fw,  eg.Efw,  s_fa, nfa, gt, gs, w);
  l1scan_rel(4, eg.rcb_s, eg.rcb_d, eg.ea_rcb, eg.Ercb, s_fa, nfa, gt, gs, w);
  l1scan_rel(5, eg.rlt_s, eg.rlt_d, eg.ea_rlt, eg.Erlt, s_fa, nfa, gt, gs, w);
}

// K3: per L1 edge (256 threads): proj(src) -> xl1 (stored), read precomputed
// xr1, attention logits via wave shuffle reduce.
__global__ void __launch_bounds__(256) k3(Inputs in, WSP w){
  __shared__ float xs[512], part[256], h0[128];
  __shared__ float pr[4];
  int t = threadIdx.x;
  int n1 = min(w.cnt[4], N1MAX);
  for (int e = blockIdx.x; e < n1; e += gridDim.x){
    int rel = w.l1rel[e], src = w.l1src[e], dslot = w.l1dslot[e];
    float ea = w.l1ea[e];
    int stype = (rel<=3)?0:(rel==4?1:2);
    proj256(stype, src, in, h0, xs, part);
    float xl1 = in.bl1[rel*256+t];
    {
      const float* W = in.Wl1 + (size_t)rel*128*256 + t;
      for (int c=0;c<128;c++) xl1 = fmaf(h0[c], W[(size_t)c*256], xl1);
    }
    w.xl1e[(size_t)e*256+t] = xl1;
    float xr1 = (rel==0) ? w.xr1c[(size_t)dslot*256+t]
              : (rel==1) ? w.xr1l[(size_t)dslot*256+t]
              : w.xr1a[((size_t)dslot*4 + (rel-2))*256 + t];
    float ev = leaky(xl1 + xr1 + ea*in.We1[rel*256+t]);
    float rd = ev * in.att1[(rel*2 + (t>>7))*128 + (t&127)];
    for (int off=32; off; off>>=1) rd += __shfl_down(rd, off);
    if ((t&63)==0) pr[t>>6] = rd;
    __syncthreads();
    if (t==0){ w.logit1[2*e]=pr[0]+pr[1]; w.logit1[2*e+1]=pr[2]+pr[3]; }
    __syncthreads();
  }
}

// K4a: one block per frontier node (128 threads). Parallel filter of the L1
// edge list into per-rel LDS match lists, then segment softmax + aggregate
// over only the matching edges. All frontier nodes run on separate CUs.
__global__ void __launch_bounds__(128) k4a(Inputs in, WSP w){
  __shared__ int   s_key[N1MAX];
  __shared__ float s_lg0[N1MAX], s_lg1[N1MAX];
  __shared__ int   s_list[4][N1MAX];
  __shared__ int   s_c[4];
  int b = blockIdx.x, t = threadIdx.x;
  int nfa = w.nf[0], nfc = w.nf[1], nfl = w.nf[2];
  int nf = nfa+nfc+nfl;
  if (b >= nf) return;
  int type, slot;
  if (b<nfa){ type=0; slot=b; }
  else if (b<nfa+nfc){ type=1; slot=b-nfa; }
  else { type=2; slot=b-nfa-nfc; }
  int n1 = min(w.cnt[4], N1MAX);
  if (t<4) s_c[t]=0;
  __syncthreads();
  for (int i=t;i<n1;i+=128){
    s_key[i] = (w.l1rel[i]<<6) | w.l1dslot[i];
    s_lg0[i] = w.logit1[2*i];
    s_lg1[i] = w.logit1[2*i+1];
  }
  __syncthreads();
  int r0,r1;
  if (type==0){ r0=2;r1=5; } else if (type==1){ r0=0;r1=0; } else { r0=1;r1=1; }
  for (int i=t;i<n1;i+=128){
    int key=s_key[i], rel=key>>6, sl=key&63;
    if (sl==slot && rel>=r0 && rel<=r1){
      int li = rel - r0;
      int pos = atomicAdd(&s_c[li],1);
      s_list[li][pos]=i;
    }
  }
  __syncthreads();
  float out=0.f;
  for (int r=r0;r<=r1;r++){
    out += in.bias1[r*128+t];
    int c = s_c[r-r0];
    if (c==0) continue;
    const int* lst = s_list[r-r0];
    float m0=-INFINITY,m1=-INFINITY;
    for (int o=0;o<c;o++){
      int i=lst[o];
      m0=fmaxf(m0,s_lg0[i]); m1=fmaxf(m1,s_lg1[i]);
    }
    float d0=0.f,d1=0.f,a0=0.f,a1=0.f;
    for (int o=0;o<c;o++){
      int i=lst[o];
      float e0=expf(s_lg0[i]-m0), e1=expf(s_lg1[i]-m1);
      d0+=e0; d1+=e1;
      a0=fmaf(e0, w.xl1e[(size_t)i*256+t],     a0);
      a1=fmaf(e1, w.xl1e[(size_t)i*256+128+t], a1);
    }
    out += 0.5f*(a0/(d0+1e-16f)+a1/(d1+1e-16f));
  }
  float v=fmaxf(out,0.f);
  if (type==0) w.x1a[(size_t)slot*128+t]=v;
  else if (type==1) w.x1c[(size_t)slot*128+t]=v;
  else w.x1l[(size_t)slot*128+t]=v;
}

// K4b: one block per L2 edge (128 threads): inline xr2 + xl2 GEMVs + logit.
// Parallelizes the cold Wr2/Wl2 streaming across CUs.
__global__ void __launch_bounds__(128) k4b(Inputs in, WSP w){
  __shared__ float xq[128], xsrc[128];
  __shared__ float pr[2];
  int e = blockIdx.x, t = threadIdx.x;
  int n2 = min(w.cnt[0], N2MAX);
  if (e >= n2) return;
  int rel = w.l2rel[e], slot = w.l2slot[e];
  float ea = w.l2ea[e];
  if (slot < 0){  // frontier-capacity overflow guard
    w.xl2e[(size_t)e*128+t]=0.f;
    if (t==0) w.logit2[e]=-INFINITY;
    return;
  }
  const float* xb = (rel<=3)? w.x1a : (rel==4? w.x1c : w.x1l);
  xq[t]   = w.x1a[t];                  // x1 of q (asset slot 0)
  xsrc[t] = xb[(size_t)slot*128+t];
  __syncthreads();
  float xr2 = in.br2[rel*128+t];
  {
    const float* W = in.Wr2 + (size_t)rel*128*128 + t;
    for (int c=0;c<128;c++) xr2 = fmaf(xq[c], W[(size_t)c*128], xr2);
  }
  float xl2 = in.bl2[rel*128+t];
  {
    const float* W = in.Wl2 + (size_t)rel*128*128 + t;
    for (int c=0;c<128;c++) xl2 = fmaf(xsrc[c], W[(size_t)c*128], xl2);
  }
  w.xl2e[(size_t)e*128+t]=xl2;
  float ev = leaky(xl2 + xr2 + ea*in.We2[rel*128+t]);
  float rd = ev * in.att2[rel*128+t];
  for (int off=32;off;off>>=1) rd += __shfl_down(rd,off);
  if ((t&63)==0) pr[t>>6]=rd;
  __syncthreads();
  if (t==0) w.logit2[e]=pr[0]+pr[1];
}

// K4c: layer-2 segment softmax + aggregate + relu, then classifier head.
__global__ void __launch_bounds__(128) k4c(Inputs in, WSP w, float* outp){
  __shared__ float x2[128], hid[128];
  __shared__ int   s_rel[N2MAX];
  __shared__ float s_lg[N2MAX];
  int t = threadIdx.x;
  int n2 = min(w.cnt[0], N2MAX);
  for (int i=t;i<n2;i+=128){ s_rel[i]=w.l2rel[i]; s_lg[i]=w.logit2[i]; }
  __syncthreads();
  float o=0.f;
  for (int r=2;r<=5;r++){
    o += in.bias2[r*128+t];
    float m=-INFINITY;
    for (int i=0;i<n2;i++) if (s_rel[i]==r) m=fmaxf(m,s_lg[i]);
    if (m==-INFINITY) continue;
    float d=0.f, acc=0.f;
    for (int i=0;i<n2;i++) if (s_rel[i]==r){
      float e=expf(s_lg[i]-m);
      d+=e;
      acc=fmaf(e, w.xl2e[(size_t)i*128+t], acc);
    }
    o += acc/(d+1e-16f);
  }
  x2[t]=fmaxf(o,0.f);
  __syncthreads();
  float a=in.bc1[t];
  for (int c=0;c<128;c++) a=fmaf(x2[c], in.Wc1[c*128+t], a);
  hid[t]=fmaxf(a,0.f);
  __syncthreads();
  if (t<3){
    float r=in.bc2[t];
    for (int c=0;c<128;c++) r=fmaf(hid[c], in.Wc2[c*3+t], r);
    outp[t]=r;
  }
}

extern "C" void kernel_launch(void* const* d_in, const int* in_sizes, int n_in,
                              void* d_out, int out_size, void* d_ws, size_t ws_size,
                              hipStream_t stream){
  Inputs in;
  in.x_asset   = (const float*)d_in[0];
  in.x_creator = (const float*)d_in[1];
  in.x_licensee= (const float*)d_in[2];
  Edges eg;
  eg.cb_s =(const int*)d_in[3];  eg.cb_d =(const int*)d_in[4];  eg.ea_cb =(const float*)d_in[5];  eg.Ecb = in_sizes[3];
  eg.lt_s =(const int*)d_in[6];  eg.lt_d =(const int*)d_in[7];  eg.ea_lt =(const float*)d_in[8];  eg.Elt = in_sizes[6];
  eg.sim_s=(const int*)d_in[9];  eg.sim_d=(const int*)d_in[10]; eg.ea_sim=(const float*)d_in[11]; eg.Esim= in_sizes[9];
  eg.fw_s =(const int*)d_in[12]; eg.fw_d =(const int*)d_in[13]; eg.ea_fw =(const float*)d_in[14]; eg.Efw = in_sizes[12];
  eg.rcb_s=(const int*)d_in[15]; eg.rcb_d=(const int*)d_in[16]; eg.ea_rcb=(const float*)d_in[17]; eg.Ercb= in_sizes[15];
  eg.rlt_s=(const int*)d_in[18]; eg.rlt_d=(const int*)d_in[19]; eg.ea_rlt=(const float*)d_in[20]; eg.Erlt= in_sizes[18];
  in.Wp_a=(const float*)d_in[21]; in.bp_a=(const float*)d_in[22];
  in.Wp_c=(const float*)d_in[23]; in.bp_c=(const float*)d_in[24];
  in.Wp_l=(const float*)d_in[25]; in.bp_l=(const float*)d_in[26];
  in.Wl1=(const float*)d_in[27]; in.bl1=(const float*)d_in[28];
  in.Wr1=(const float*)d_in[29]; in.br1=(const float*)d_in[30];
  in.We1=(const float*)d_in[31]; in.att1=(const float*)d_in[32]; in.bias1=(const float*)d_in[33];
  in.Wl2=(const float*)d_in[34]; in.bl2=(const float*)d_in[35];
  in.Wr2=(const float*)d_in[36]; in.br2=(const float*)d_in[37];
  in.We2=(const float*)d_in[38]; in.att2=(const float*)d_in[39]; in.bias2=(const float*)d_in[40];
  in.Wc1=(const float*)d_in[41]; in.bc1=(const float*)d_in[42];
  in.Wc2=(const float*)d_in[43]; in.bc2=(const float*)d_in[44];
  const int* qptr = (const int*)d_in[45];
  float* outp = (float*)d_out;

  char* p = (char*)d_ws;
  auto carve = [&](size_t n)->char*{ char* r = p; p += ((n + 255) & ~(size_t)255); return r; };
  WSP w;
  w.cnt  = (int*)carve(16*4);
  w.nf   = (int*)carve(3*4);
  w.l2rel=(int*)carve(N2MAX*4); w.l2src=(int*)carve(N2MAX*4);
  w.l2ea=(float*)carve(N2MAX*4); w.l2slot=(int*)carve(N2MAX*4);
  w.l1rel=(int*)carve(N1MAX*4); w.l1src=(int*)carve(N1MAX*4);
  w.l1dslot=(int*)carve(N1MAX*4); w.l1ea=(float*)carve(N1MAX*4);
  w.xr1a=(float*)carve((size_t)FAMAX*4*256*4);
  w.xr1c=(float*)carve((size_t)FCMAX*256*4);
  w.xr1l=(float*)carve((size_t)FLMAX*256*4);
  w.xl1e=(float*)carve((size_t)N1MAX*256*4);
  w.logit1=(float*)carve((size_t)N1MAX*2*4);
  w.x1a=(float*)carve((size_t)FAMAX*128*4);
  w.x1c=(float*)carve((size_t)FCMAX*128*4);
  w.x1l=(float*)carve((size_t)FLMAX*128*4);
  w.xl2e=(float*)carve((size_t)N2MAX*128*4);
  w.logit2=(float*)carve(N2MAX*4);

  hipMemsetAsync(w.cnt, 0, 64, stream);   // only the two atomic counters

  int quad2 = (eg.Esim + eg.Efw + eg.Ercb + eg.Erlt)/4 + 1;
  int b1 = (quad2 + 255)/256; if (b1 > 1024) b1 = 1024;
  k1<<<b1, 256, 0, stream>>>(eg, qptr, w);
  k2<<<PROJB + SCANB, 256, 0, stream>>>(in, eg, w, qptr);
  k3<<<256, 256, 0, stream>>>(in, w);
  k4a<<<FAMAX + FCMAX + FLMAX, 128, 0, stream>>>(in, w);
  k4b<<<N2MAX, 128, 0, stream>>>(in, w);
  k4c<<<1, 128, 0, stream>>>(in, w, outp);
}

// Round 7
// 288.097 us; speedup vs baseline: 2.1348x; 1.0231x over previous
//
#include <hip/hip_runtime.h>
#include <math.h>

// R13: resubmit of R12 (infra failure, same signature as R2's flake). Only
// change: pf4 keep-alive is now an asm volatile register sink (rule #17)
// instead of a float-compare-and-store.
// R12 design: (a) k1 gains 96 prefetch blocks streaming all weights (~2.7 MB)
// into the memory-side L3 while the edge scan runs (harness poison evicts
// caches every iteration -> downstream stages were paying cold-HBM ~900cyc
// per miss on latency-critical GEMV chains); (b) k4a/k4b/k4c widened to 256
// threads (split-K / per-head split) for 2x outstanding loads.
#define FAMAX 64     // dst-frontier assets (expected ~11)
#define FCMAX 32     // dst-frontier creators (expected ~1)
#define FLMAX 32     // dst-frontier licensees (expected ~2)
#define N1MAX 512    // layer-1 edges into frontier (expected ~125)
#define N2MAX 128    // layer-2 edges into query (expected ~9)
#define PROJB 128    // k2 blocks reserved for frontier projections
#define SCANB 512    // k2 blocks doing the L1 edge scan
#define PFB   96     // k1 prefetch blocks

struct Inputs {
  const float *x_asset, *x_creator, *x_licensee;
  const float *Wp_a,*bp_a,*Wp_c,*bp_c,*Wp_l,*bp_l;
  const float *Wl1,*bl1,*Wr1,*br1,*We1,*att1,*bias1;
  const float *Wl2,*bl2,*Wr2,*br2,*We2,*att2,*bias2;
  const float *Wc1,*bc1,*Wc2,*bc2;
};

struct Edges {
  const int *cb_s,*cb_d;  const float* ea_cb;  int Ecb;
  const int *lt_s,*lt_d;  const float* ea_lt;  int Elt;
  const int *sim_s,*sim_d;const float* ea_sim; int Esim;
  const int *fw_s,*fw_d;  const float* ea_fw;  int Efw;
  const int *rcb_s,*rcb_d;const float* ea_rcb; int Ercb;
  const int *rlt_s,*rlt_d;const float* ea_rlt; int Erlt;
};

struct WSP {
  int* cnt;             // [0]=n_l2e [4]=n_l1e  (zeroed by 64B memset)
  int* nf;              // [3] frontier counts (written by k2 block 0)
  int* l2rel; int* l2src; float* l2ea; int* l2slot;
  int* l1rel; int* l1src; int* l1dslot; float* l1ea;
  float* xr1a;          // [FAMAX][4][256]  dst-side xr1 for asset nodes, rels 2..5
  float* xr1c;          // [FCMAX][256]     rel 0
  float* xr1l;          // [FLMAX][256]     rel 1
  float* xl1e;          // [N1MAX][256]
  float* logit1;        // [N1MAX][2]
  float *x1a,*x1c,*x1l; // layer-1 outputs [F*MAX][128]
  float* xl2e;          // [N2MAX][128]
  float* logit2;        // [N2MAX]
};

__device__ __forceinline__ float leaky(float x){ return x > 0.f ? x : 0.2f*x; }

__device__ __forceinline__ int fsearch(const int* list, int n, int v){
  for (int k=0;k<n;k++) if (list[k]==v) return k;
  return -1;
}

// sum n floats (n%4==0) with float4 loads — L3 warmer, result kept live
// by the caller's asm sink.
__device__ __forceinline__ float pf4(const float* p, int n, int gt, int gs){
  float s = 0.f;
  const float4* p4 = (const float4*)p;
  int n4 = n >> 2;
  for (int i = gt; i < n4; i += gs){ float4 v = p4[i]; s += v.x+v.y+v.z+v.w; }
  return s;
}

// 128-d projection of `node` of `type` into LDS h0[] using 256 threads.
__device__ __forceinline__ void proj256(int type, int node, const Inputs& in,
                                        float* h0, float* xs, float* part){
  int t = threadIdx.x;
  if (type == 0){
    xs[t]       = in.x_asset[(size_t)node*512 + t];
    xs[t + 256] = in.x_asset[(size_t)node*512 + t + 256];
    __syncthreads();
    int j = t & 127, g2 = t >> 7;
    float acc = 0.f;
    const float* W = in.Wp_a + (size_t)g2*256*128 + j;
    const float* xg = xs + g2*256;
    for (int k=0;k<256;k++) acc = fmaf(xg[k], W[(size_t)k*128], acc);
    part[t] = acc;
    __syncthreads();
    if (t < 128) h0[t] = in.bp_a[t] + part[t] + part[128 + t];
  } else if (type == 1){
    if (t < 128)
      h0[t] = in.bp_c[t] + in.x_creator[node*2]*in.Wp_c[t]
            + in.x_creator[node*2+1]*in.Wp_c[128+t];
  } else {
    if (t < 128)
      h0[t] = in.bp_l[t] + in.x_licensee[node]*in.Wp_l[t];
  }
  __syncthreads();
}

__device__ __forceinline__ void l2hit(int rel, int s, float e, WSP& w){
  int k = atomicAdd(&w.cnt[0], 1);
  if (k < N2MAX){ w.l2rel[k]=rel; w.l2src[k]=s; w.l2ea[k]=e; }
}

__device__ __forceinline__ void l2scan_rel(int rel, const int* sp, const int* dp,
                                           const float* ep, int E, int q,
                                           int gt, int gs, WSP& w){
  int nq = E >> 2;
  const int4* d4 = (const int4*)dp;
  for (int i = gt; i < nq; i += gs){
    int4 d = d4[i];
    int j = i << 2;
    if (d.x == q) l2hit(rel, sp[j],   ep[j],   w);
    if (d.y == q) l2hit(rel, sp[j+1], ep[j+1], w);
    if (d.z == q) l2hit(rel, sp[j+2], ep[j+2], w);
    if (d.w == q) l2hit(rel, sp[j+3], ep[j+3], w);
  }
  int base = nq << 2, tail = E - base;
  if (gt < tail){
    int j = base + gt;
    if (dp[j] == q) l2hit(rel, sp[j], ep[j], w);
  }
}

__device__ __forceinline__ void l1hit(int rel, int s, int slot, float e, WSP& w){
  int k = atomicAdd(&w.cnt[4], 1);
  if (k < N1MAX){ w.l1rel[k]=rel; w.l1src[k]=s; w.l1dslot[k]=slot; w.l1ea[k]=e; }
}

__device__ __forceinline__ void l1scan_rel(int rel, const int* sp, const int* dp,
                                           const float* ep, int E,
                                           const int* flist, int fn,
                                           int gt, int gs, WSP& w){
  int nq = E >> 2;
  const int4* d4 = (const int4*)dp;
  for (int i = gt; i < nq; i += gs){
    int4 d = d4[i];
    int j = i << 2;
    int s0 = fsearch(flist, fn, d.x); if (s0>=0) l1hit(rel, sp[j],   s0, ep[j],   w);
    int s1 = fsearch(flist, fn, d.y); if (s1>=0) l1hit(rel, sp[j+1], s1, ep[j+1], w);
    int s2 = fsearch(flist, fn, d.z); if (s2>=0) l1hit(rel, sp[j+2], s2, ep[j+2], w);
    int s3 = fsearch(flist, fn, d.w); if (s3>=0) l1hit(rel, sp[j+3], s3, ep[j+3], w);
  }
  int base = nq << 2, tail = E - base;
  if (gt < tail){
    int j = base + gt;
    int s0 = fsearch(flist, fn, dp[j]);
    if (s0>=0) l1hit(rel, sp[j], s0, ep[j], w);
  }
}

// K1: blocks [0,scanB) scan Asset-targeting relations for dst == q -> L2 edge
// list. Blocks [scanB, scanB+PFB) stream all weights into the memory-side L3.
__global__ void __launch_bounds__(256) k1(Edges eg, Inputs in, const int* qptr,
                                          WSP w, int scanB){
  if ((int)blockIdx.x >= scanB){
    int gt = (blockIdx.x - scanB)*256 + threadIdx.x, gs = PFB*256;
    float s = 0.f;
    s += pf4(in.Wp_a, 512*128, gt, gs);
    s += pf4(in.Wr1, 6*128*256, gt, gs);
    s += pf4(in.Wl1, 6*128*256, gt, gs);
    s += pf4(in.Wr2, 6*128*128, gt, gs);
    s += pf4(in.Wl2, 6*128*128, gt, gs);
    s += pf4(in.Wc1, 128*128, gt, gs);
    s += pf4(in.We1, 6*256, gt, gs);
    s += pf4(in.att1, 6*256, gt, gs);
    s += pf4(in.bl1, 6*256, gt, gs);
    s += pf4(in.br1, 6*256, gt, gs);
    s += pf4(in.bias1, 6*128, gt, gs);
    s += pf4(in.We2, 6*128, gt, gs);
    s += pf4(in.att2, 6*128, gt, gs);
    s += pf4(in.bias2, 6*128, gt, gs);
    s += pf4(in.bl2, 6*128, gt, gs);
    s += pf4(in.br2, 6*128, gt, gs);
    s += pf4(in.Wc2, 128*3, gt, gs);
    s += pf4(in.bc1, 128, gt, gs);
    asm volatile("" :: "v"(s));   // keep the prefetch loads live (rule #17)
    return;
  }
  int q = qptr[0];
  int gt = blockIdx.x*256 + threadIdx.x, gs = scanB*256;
  l2scan_rel(2, eg.sim_s, eg.sim_d, eg.ea_sim, eg.Esim, q, gt, gs, w);
  l2scan_rel(3, eg.fw_s,  eg.fw_d,  eg.ea_fw,  eg.Efw,  q, gt, gs, w);
  l2scan_rel(4, eg.rcb_s, eg.rcb_d, eg.ea_rcb, eg.Ercb, q, gt, gs, w);
  l2scan_rel(5, eg.rlt_s, eg.rlt_d, eg.ea_rlt, eg.Erlt, q, gt, gs, w);
}

// K2: every block dedups the L2 list into LDS frontier lists (deterministic,
// identical across blocks). Blocks [0,PROJB): project frontier node b and
// precompute its xr1 vectors. Blocks [PROJB, PROJB+SCANB): scan all 6
// relations for dst-in-frontier -> L1 edge list. Both run concurrently.
__global__ void __launch_bounds__(256) k2(Inputs in, Edges eg, WSP w, const int* qptr){
  __shared__ float xs[512], part[256], h0[128];
  __shared__ int s_fa[FAMAX], s_fc[FCMAX], s_fl[FLMAX];
  __shared__ int s_nf[3];
  __shared__ int s_l2rel[N2MAX], s_l2src[N2MAX], s_l2slot[N2MAX];
  int b = blockIdx.x, t = threadIdx.x;
  int q = qptr[0];
  int n2 = min(w.cnt[0], N2MAX);
  for (int i=t; i<n2; i+=256){ s_l2rel[i]=w.l2rel[i]; s_l2src[i]=w.l2src[i]; }
  __syncthreads();
  if (t==0){
    int nfa=0,nfc=0,nfl=0;
    s_fa[nfa++]=q;                      // q is always asset slot 0
    for (int i=0;i<n2;i++){
      int rel=s_l2rel[i], src=s_l2src[i], s=-1;
      if (rel<=3){ s=fsearch(s_fa,nfa,src); if (s<0 && nfa<FAMAX){ s=nfa; s_fa[nfa++]=src; } }
      else if (rel==4){ s=fsearch(s_fc,nfc,src); if (s<0 && nfc<FCMAX){ s=nfc; s_fc[nfc++]=src; } }
      else { s=fsearch(s_fl,nfl,src); if (s<0 && nfl<FLMAX){ s=nfl; s_fl[nfl++]=src; } }
      s_l2slot[i]=s;                    // -1 on frontier-capacity overflow
    }
    s_nf[0]=nfa; s_nf[1]=nfc; s_nf[2]=nfl;
    if (b==0){
      w.nf[0]=nfa; w.nf[1]=nfc; w.nf[2]=nfl;
      for (int i=0;i<n2;i++) w.l2slot[i]=s_l2slot[i];
    }
  }
  __syncthreads();
  int nfa=s_nf[0], nfc=s_nf[1], nfl=s_nf[2];
  if (b < PROJB){
    int nf = nfa+nfc+nfl;
    if (b < nf){
      int type, slot, node;
      if (b<nfa){ type=0; slot=b; node=s_fa[slot]; }
      else if (b<nfa+nfc){ type=1; slot=b-nfa; node=s_fc[slot]; }
      else { type=2; slot=b-nfa-nfc; node=s_fl[slot]; }
      proj256(type, node, in, h0, xs, part);
      if (type==0){
        for (int rr=0; rr<4; rr++){
          int r = 2+rr;
          float acc = in.br1[r*256+t];
          const float* W = in.Wr1 + (size_t)r*128*256 + t;
          for (int c=0;c<128;c++) acc = fmaf(h0[c], W[(size_t)c*256], acc);
          w.xr1a[((size_t)slot*4+rr)*256 + t] = acc;
        }
      } else if (type==1){
        float acc = in.br1[t];
        const float* W = in.Wr1 + t;
        for (int c=0;c<128;c++) acc = fmaf(h0[c], W[(size_t)c*256], acc);
        w.xr1c[(size_t)slot*256+t] = acc;
      } else {
        float acc = in.br1[256+t];
        const float* W = in.Wr1 + (size_t)128*256 + t;
        for (int c=0;c<128;c++) acc = fmaf(h0[c], W[(size_t)c*256], acc);
        w.xr1l[(size_t)slot*256+t] = acc;
      }
    }
    return;
  }
  int gt = (b-PROJB)*256 + t, gs = SCANB*256;
  l1scan_rel(0, eg.cb_s,  eg.cb_d,  eg.ea_cb,  eg.Ecb,  s_fc, nfc, gt, gs, w);
  l1scan_rel(1, eg.lt_s,  eg.lt_d,  eg.ea_lt,  eg.Elt,  s_fl, nfl, gt, gs, w);
  l1scan_rel(2, eg.sim_s, eg.sim_d, eg.ea_sim, eg.Esim, s_fa, nfa, gt, gs, w);
  l1scan_rel(3, eg.fw_s,  eg.fw_d,  eg.ea_fw,  eg.Efw,  s_fa, nfa, gt, gs, w);
  l1scan_rel(4, eg.rcb_s, eg.rcb_d, eg.ea_rcb, eg.Ercb, s_fa, nfa, gt, gs, w);
  l1scan_rel(5, eg.rlt_s, eg.rlt_d, eg.ea_rlt, eg.Erlt, s_fa, nfa, gt, gs, w);
}

// K3: per L1 edge (256 threads): proj(src) -> xl1 (stored), read precomputed
// xr1, attention logits via wave shuffle reduce.
__global__ void __launch_bounds__(256) k3(Inputs in, WSP w){
  __shared__ float xs[512], part[256], h0[128];
  __shared__ float pr[4];
  int t = threadIdx.x;
  int n1 = min(w.cnt[4], N1MAX);
  for (int e = blockIdx.x; e < n1; e += gridDim.x){
    int rel = w.l1rel[e], src = w.l1src[e], dslot = w.l1dslot[e];
    float ea = w.l1ea[e];
    int stype = (rel<=3)?0:(rel==4?1:2);
    proj256(stype, src, in, h0, xs, part);
    float xl1 = in.bl1[rel*256+t];
    {
      const float* W = in.Wl1 + (size_t)rel*128*256 + t;
      for (int c=0;c<128;c++) xl1 = fmaf(h0[c], W[(size_t)c*256], xl1);
    }
    w.xl1e[(size_t)e*256+t] = xl1;
    float xr1 = (rel==0) ? w.xr1c[(size_t)dslot*256+t]
              : (rel==1) ? w.xr1l[(size_t)dslot*256+t]
              : w.xr1a[((size_t)dslot*4 + (rel-2))*256 + t];
    float ev = leaky(xl1 + xr1 + ea*in.We1[rel*256+t]);
    float rd = ev * in.att1[(rel*2 + (t>>7))*128 + (t&127)];
    for (int off=32; off; off>>=1) rd += __shfl_down(rd, off);
    if ((t&63)==0) pr[t>>6] = rd;
    __syncthreads();
    if (t==0){ w.logit1[2*e]=pr[0]+pr[1]; w.logit1[2*e+1]=pr[2]+pr[3]; }
    __syncthreads();
  }
}

// K4a: one block per frontier node, 256 threads (lane j = t&127, head h =
// t>>7). Parallel filter into per-rel LDS lists, per-head segment softmax +
// aggregate (2x load parallelism vs the 128-thread version), head-combine
// via LDS.
__global__ void __launch_bounds__(256) k4a(Inputs in, WSP w){
  __shared__ int   s_key[N1MAX];
  __shared__ float s_lg0[N1MAX], s_lg1[N1MAX];
  __shared__ int   s_list[4][N1MAX];
  __shared__ int   s_c[4];
  __shared__ float sA[256];
  int b = blockIdx.x, t = threadIdx.x;
  int nfa = w.nf[0], nfc = w.nf[1], nfl = w.nf[2];
  int nf = nfa+nfc+nfl;
  if (b >= nf) return;
  int type, slot;
  if (b<nfa){ type=0; slot=b; }
  else if (b<nfa+nfc){ type=1; slot=b-nfa; }
  else { type=2; slot=b-nfa-nfc; }
  int n1 = min(w.cnt[4], N1MAX);
  if (t<4) s_c[t]=0;
  __syncthreads();
  for (int i=t;i<n1;i+=256){
    s_key[i] = (w.l1rel[i]<<6) | w.l1dslot[i];
    float2 L = ((const float2*)w.logit1)[i];
    s_lg0[i] = L.x; s_lg1[i] = L.y;
  }
  __syncthreads();
  int r0,r1;
  if (type==0){ r0=2;r1=5; } else if (type==1){ r0=0;r1=0; } else { r0=1;r1=1; }
  for (int i=t;i<n1;i+=256){
    int key=s_key[i], rel=key>>6, sl=key&63;
    if (sl==slot && rel>=r0 && rel<=r1){
      int li = rel - r0;
      int pos = atomicAdd(&s_c[li],1);
      s_list[li][pos]=i;
    }
  }
  __syncthreads();
  int j = t&127, h = t>>7;
  const float* lg = h ? s_lg1 : s_lg0;
  float out = 0.f;   // meaningful for t<128
  for (int r=r0;r<=r1;r++){
    int li = r-r0, c = s_c[li];
    float av = 0.f;
    if (c>0){
      const int* lst = s_list[li];
      float m=-INFINITY;
      for (int o=0;o<c;o++) m = fmaxf(m, lg[lst[o]]);
      float d=0.f, a=0.f;
      for (int o=0;o<c;o++){
        int i = lst[o];
        float e = expf(lg[i]-m);
        d += e;
        a = fmaf(e, w.xl1e[(size_t)i*256 + h*128 + j], a);
      }
      av = a/(d+1e-16f);
    }
    sA[t] = av;
    __syncthreads();
    if (t<128) out += in.bias1[r*128+j] + 0.5f*(sA[j]+sA[j+128]);
    __syncthreads();
  }
  if (t<128){
    float v = fmaxf(out, 0.f);
    if (type==0) w.x1a[(size_t)slot*128+j]=v;
    else if (type==1) w.x1c[(size_t)slot*128+j]=v;
    else w.x1l[(size_t)slot*128+j]=v;
  }
}

// K4b: one block per L2 edge, 256 threads: xr2 + xl2 GEMVs split-K by 2
// (2x outstanding loads), then logit.
__global__ void __launch_bounds__(256) k4b(Inputs in, WSP w){
  __shared__ float xq[128], xsrc[128], px[256], pl[256];
  __shared__ float pr[2];
  int e = blockIdx.x, t = threadIdx.x;
  int n2 = min(w.cnt[0], N2MAX);
  if (e >= n2) return;
  int rel = w.l2rel[e], slot = w.l2slot[e];
  float ea = w.l2ea[e];
  if (slot < 0){  // frontier-capacity overflow guard
    if (t<128) w.xl2e[(size_t)e*128+t]=0.f;
    if (t==0) w.logit2[e]=-INFINITY;
    return;
  }
  const float* xb = (rel<=3)? w.x1a : (rel==4? w.x1c : w.x1l);
  if (t<128){ xq[t] = w.x1a[t]; xsrc[t] = xb[(size_t)slot*128+t]; }
  __syncthreads();
  int j = t&127, g = t>>7;
  float axr=0.f, axl=0.f;
  {
    const float* Wr = in.Wr2 + (size_t)rel*128*128 + j;
    const float* Wl = in.Wl2 + (size_t)rel*128*128 + j;
    for (int c=g*64; c<g*64+64; c++){
      axr = fmaf(xq[c],   Wr[(size_t)c*128], axr);
      axl = fmaf(xsrc[c], Wl[(size_t)c*128], axl);
    }
  }
  px[t]=axr; pl[t]=axl;
  __syncthreads();
  float rd = 0.f;
  if (t<128){
    float xr2 = in.br2[rel*128+j] + px[j] + px[j+128];
    float xl2 = in.bl2[rel*128+j] + pl[j] + pl[j+128];
    w.xl2e[(size_t)e*128+j] = xl2;
    float ev = leaky(xl2 + xr2 + ea*in.We2[rel*128+j]);
    rd = ev * in.att2[rel*128+j];
  }
  for (int off=32;off;off>>=1) rd += __shfl_down(rd,off);
  if ((t&63)==0 && t<128) pr[t>>6]=rd;
  __syncthreads();
  if (t==0) w.logit2[e] = pr[0]+pr[1];
}

// K4c: layer-2 segment softmax + aggregate + relu, classifier with split-K
// Wc1 GEMV (256 threads).
__global__ void __launch_bounds__(256) k4c(Inputs in, WSP w, float* outp){
  __shared__ float x2[128], hid[128], part[256];
  __shared__ int   s_rel[N2MAX];
  __shared__ float s_lg[N2MAX];
  int t = threadIdx.x;
  int n2 = min(w.cnt[0], N2MAX);
  for (int i=t;i<n2;i+=256){ s_rel[i]=w.l2rel[i]; s_lg[i]=w.logit2[i]; }
  __syncthreads();
  if (t<128){
    float o=0.f;
    for (int r=2;r<=5;r++){
      o += in.bias2[r*128+t];
      float m=-INFINITY;
      for (int i=0;i<n2;i++) if (s_rel[i]==r) m=fmaxf(m,s_lg[i]);
      if (m==-INFINITY) continue;
      float d=0.f, acc=0.f;
      for (int i=0;i<n2;i++) if (s_rel[i]==r){
        float e=expf(s_lg[i]-m);
        d+=e;
        acc=fmaf(e, w.xl2e[(size_t)i*128+t], acc);
      }
      o += acc/(d+1e-16f);
    }
    x2[t]=fmaxf(o,0.f);
  }
  __syncthreads();
  int j = t&127, g = t>>7;
  float a=0.f;
  for (int c=g*64;c<g*64+64;c++) a=fmaf(x2[c], in.Wc1[(size_t)c*128+j], a);
  part[t]=a;
  __syncthreads();
  if (t<128) hid[t]=fmaxf(in.bc1[t]+part[t]+part[t+128], 0.f);
  __syncthreads();
  if (t<3){
    float r=in.bc2[t];
    for (int c=0;c<128;c++) r=fmaf(hid[c], in.Wc2[c*3+t], r);
    outp[t]=r;
  }
}

extern "C" void kernel_launch(void* const* d_in, const int* in_sizes, int n_in,
                              void* d_out, int out_size, void* d_ws, size_t ws_size,
                              hipStream_t stream){
  Inputs in;
  in.x_asset   = (const float*)d_in[0];
  in.x_creator = (const float*)d_in[1];
  in.x_licensee= (const float*)d_in[2];
  Edges eg;
  eg.cb_s =(const int*)d_in[3];  eg.cb_d =(const int*)d_in[4];  eg.ea_cb =(const float*)d_in[5];  eg.Ecb = in_sizes[3];
  eg.lt_s =(const int*)d_in[6];  eg.lt_d =(const int*)d_in[7];  eg.ea_lt =(const float*)d_in[8];  eg.Elt = in_sizes[6];
  eg.sim_s=(const int*)d_in[9];  eg.sim_d=(const int*)d_in[10]; eg.ea_sim=(const float*)d_in[11]; eg.Esim= in_sizes[9];
  eg.fw_s =(const int*)d_in[12]; eg.fw_d =(const int*)d_in[13]; eg.ea_fw =(const float*)d_in[14]; eg.Efw = in_sizes[12];
  eg.rcb_s=(const int*)d_in[15]; eg.rcb_d=(const int*)d_in[16]; eg.ea_rcb=(const float*)d_in[17]; eg.Ercb= in_sizes[15];
  eg.rlt_s=(const int*)d_in[18]; eg.rlt_d=(const int*)d_in[19]; eg.ea_rlt=(const float*)d_in[20]; eg.Erlt= in_sizes[18];
  in.Wp_a=(const float*)d_in[21]; in.bp_a=(const float*)d_in[22];
  in.Wp_c=(const float*)d_in[23]; in.bp_c=(const float*)d_in[24];
  in.Wp_l=(const float*)d_in[25]; in.bp_l=(const float*)d_in[26];
  in.Wl1=(const float*)d_in[27]; in.bl1=(const float*)d_in[28];
  in.Wr1=(const float*)d_in[29]; in.br1=(const float*)d_in[30];
  in.We1=(const float*)d_in[31]; in.att1=(const float*)d_in[32]; in.bias1=(const float*)d_in[33];
  in.Wl2=(const float*)d_in[34]; in.bl2=(const float*)d_in[35];
  in.Wr2=(const float*)d_in[36]; in.br2=(const float*)d_in[37];
  in.We2=(const float*)d_in[38]; in.att2=(const float*)d_in[39]; in.bias2=(const float*)d_in[40];
  in.Wc1=(const float*)d_in[41]; in.bc1=(const float*)d_in[42];
  in.Wc2=(const float*)d_in[43]; in.bc2=(const float*)d_in[44];
  const int* qptr = (const int*)d_in[45];
  float* outp = (float*)d_out;

  char* p = (char*)d_ws;
  auto carve = [&](size_t n)->char*{ char* r = p; p += ((n + 255) & ~(size_t)255); return r; };
  WSP w;
  w.cnt  = (int*)carve(16*4);
  w.nf   = (int*)carve(3*4);
  w.l2rel=(int*)carve(N2MAX*4); w.l2src=(int*)carve(N2MAX*4);
  w.l2ea=(float*)carve(N2MAX*4); w.l2slot=(int*)carve(N2MAX*4);
  w.l1rel=(int*)carve(N1MAX*4); w.l1src=(int*)carve(N1MAX*4);
  w.l1dslot=(int*)carve(N1MAX*4); w.l1ea=(float*)carve(N1MAX*4);
  w.xr1a=(float*)carve((size_t)FAMAX*4*256*4);
  w.xr1c=(float*)carve((size_t)FCMAX*256*4);
  w.xr1l=(float*)carve((size_t)FLMAX*256*4);
  w.xl1e=(float*)carve((size_t)N1MAX*256*4);
  w.logit1=(float*)carve((size_t)N1MAX*2*4);
  w.x1a=(float*)carve((size_t)FAMAX*128*4);
  w.x1c=(float*)carve((size_t)FCMAX*128*4);
  w.x1l=(float*)carve((size_t)FLMAX*128*4);
  w.xl2e=(float*)carve((size_t)N2MAX*128*4);
  w.logit2=(float*)carve(N2MAX*4);

  hipMemsetAsync(w.cnt, 0, 64, stream);   // only the two atomic counters

  int quad2 = (eg.Esim + eg.Efw + eg.Ercb + eg.Erlt)/4 + 1;
  int b1 = (quad2 + 255)/256; if (b1 > 1024) b1 = 1024;
  k1<<<b1 + PFB, 256, 0, stream>>>(eg, in, qptr, w, b1);
  k2<<<PROJB + SCANB, 256, 0, stream>>>(in, eg, w, qptr);
  k3<<<256, 256, 0, stream>>>(in, w);
  k4a<<<FAMAX + FCMAX + FLMAX, 256, 0, stream>>>(in, w);
  k4b<<<N2MAX, 256, 0, stream>>>(in, w);
  k4c<<<1, 256, 0, stream>>>(in, w, outp);
}

// Round 8
// 286.659 us; speedup vs baseline: 2.1455x; 1.0050x over previous
//
#include <hip/hip_runtime.h>
#include <math.h>

// R14: dispatch-count attack. 7 -> 5 stream ops: k4a+k4b+k4c fused into k45.
// Each L2-edge block aggregates layer-1 output for BOTH endpoints (src node
// and q) entirely in LDS (kills k4a + the x1 global round-trip), then does
// the xr2/xl2 GEMVs + logit. The layer-2 softmax + classifier tail runs in
// the last-finishing block (device-scope ticket, G16 pattern).
// k1 (scan + L3 weight prefetch), k2, k3 identical to R13.
#define FAMAX 64     // dst-frontier assets (expected ~11)
#define FCMAX 32     // dst-frontier creators (expected ~1)
#define FLMAX 32     // dst-frontier licensees (expected ~2)
#define N1MAX 512    // layer-1 edges into frontier (expected ~125)
#define N2MAX 128    // layer-2 edges into query (expected ~9)
#define PROJB 128    // k2 blocks reserved for frontier projections
#define SCANB 512    // k2 blocks doing the L1 edge scan
#define PFB   96     // k1 prefetch blocks

struct Inputs {
  const float *x_asset, *x_creator, *x_licensee;
  const float *Wp_a,*bp_a,*Wp_c,*bp_c,*Wp_l,*bp_l;
  const float *Wl1,*bl1,*Wr1,*br1,*We1,*att1,*bias1;
  const float *Wl2,*bl2,*Wr2,*br2,*We2,*att2,*bias2;
  const float *Wc1,*bc1,*Wc2,*bc2;
};

struct Edges {
  const int *cb_s,*cb_d;  const float* ea_cb;  int Ecb;
  const int *lt_s,*lt_d;  const float* ea_lt;  int Elt;
  const int *sim_s,*sim_d;const float* ea_sim; int Esim;
  const int *fw_s,*fw_d;  const float* ea_fw;  int Efw;
  const int *rcb_s,*rcb_d;const float* ea_rcb; int Ercb;
  const int *rlt_s,*rlt_d;const float* ea_rlt; int Erlt;
};

struct WSP {
  int* cnt;             // [0]=n_l2e [4]=n_l1e [12]=k45 ticket (zeroed by 64B memset)
  int* nf;              // [3] frontier counts (written by k2 block 0)
  int* l2rel; int* l2src; float* l2ea; int* l2slot;
  int* l1rel; int* l1src; int* l1dslot; float* l1ea;
  float* xr1a;          // [FAMAX][4][256]  dst-side xr1 for asset nodes, rels 2..5
  float* xr1c;          // [FCMAX][256]     rel 0
  float* xr1l;          // [FLMAX][256]     rel 1
  float* xl1e;          // [N1MAX][256]
  float* logit1;        // [N1MAX][2]
  float* xl2e;          // [N2MAX][128]
  float* logit2;        // [N2MAX]
};

__device__ __forceinline__ float leaky(float x){ return x > 0.f ? x : 0.2f*x; }

__device__ __forceinline__ int fsearch(const int* list, int n, int v){
  for (int k=0;k<n;k++) if (list[k]==v) return k;
  return -1;
}

// sum n floats (n%4==0) with float4 loads — L3 warmer, result kept live
// by the caller's asm sink.
__device__ __forceinline__ float pf4(const float* p, int n, int gt, int gs){
  float s = 0.f;
  const float4* p4 = (const float4*)p;
  int n4 = n >> 2;
  for (int i = gt; i < n4; i += gs){ float4 v = p4[i]; s += v.x+v.y+v.z+v.w; }
  return s;
}

// 128-d projection of `node` of `type` into LDS h0[] using 256 threads.
__device__ __forceinline__ void proj256(int type, int node, const Inputs& in,
                                        float* h0, float* xs, float* part){
  int t = threadIdx.x;
  if (type == 0){
    xs[t]       = in.x_asset[(size_t)node*512 + t];
    xs[t + 256] = in.x_asset[(size_t)node*512 + t + 256];
    __syncthreads();
    int j = t & 127, g2 = t >> 7;
    float acc = 0.f;
    const float* W = in.Wp_a + (size_t)g2*256*128 + j;
    const float* xg = xs + g2*256;
    for (int k=0;k<256;k++) acc = fmaf(xg[k], W[(size_t)k*128], acc);
    part[t] = acc;
    __syncthreads();
    if (t < 128) h0[t] = in.bp_a[t] + part[t] + part[128 + t];
  } else if (type == 1){
    if (t < 128)
      h0[t] = in.bp_c[t] + in.x_creator[node*2]*in.Wp_c[t]
            + in.x_creator[node*2+1]*in.Wp_c[128+t];
  } else {
    if (t < 128)
      h0[t] = in.bp_l[t] + in.x_licensee[node]*in.Wp_l[t];
  }
  __syncthreads();
}

__device__ __forceinline__ void l2hit(int rel, int s, float e, WSP& w){
  int k = atomicAdd(&w.cnt[0], 1);
  if (k < N2MAX){ w.l2rel[k]=rel; w.l2src[k]=s; w.l2ea[k]=e; }
}

__device__ __forceinline__ void l2scan_rel(int rel, const int* sp, const int* dp,
                                           const float* ep, int E, int q,
                                           int gt, int gs, WSP& w){
  int nq = E >> 2;
  const int4* d4 = (const int4*)dp;
  for (int i = gt; i < nq; i += gs){
    int4 d = d4[i];
    int j = i << 2;
    if (d.x == q) l2hit(rel, sp[j],   ep[j],   w);
    if (d.y == q) l2hit(rel, sp[j+1], ep[j+1], w);
    if (d.z == q) l2hit(rel, sp[j+2], ep[j+2], w);
    if (d.w == q) l2hit(rel, sp[j+3], ep[j+3], w);
  }
  int base = nq << 2, tail = E - base;
  if (gt < tail){
    int j = base + gt;
    if (dp[j] == q) l2hit(rel, sp[j], ep[j], w);
  }
}

__device__ __forceinline__ void l1hit(int rel, int s, int slot, float e, WSP& w){
  int k = atomicAdd(&w.cnt[4], 1);
  if (k < N1MAX){ w.l1rel[k]=rel; w.l1src[k]=s; w.l1dslot[k]=slot; w.l1ea[k]=e; }
}

__device__ __forceinline__ void l1scan_rel(int rel, const int* sp, const int* dp,
                                           const float* ep, int E,
                                           const int* flist, int fn,
                                           int gt, int gs, WSP& w){
  int nq = E >> 2;
  const int4* d4 = (const int4*)dp;
  for (int i = gt; i < nq; i += gs){
    int4 d = d4[i];
    int j = i << 2;
    int s0 = fsearch(flist, fn, d.x); if (s0>=0) l1hit(rel, sp[j],   s0, ep[j],   w);
    int s1 = fsearch(flist, fn, d.y); if (s1>=0) l1hit(rel, sp[j+1], s1, ep[j+1], w);
    int s2 = fsearch(flist, fn, d.z); if (s2>=0) l1hit(rel, sp[j+2], s2, ep[j+2], w);
    int s3 = fsearch(flist, fn, d.w); if (s3>=0) l1hit(rel, sp[j+3], s3, ep[j+3], w);
  }
  int base = nq << 2, tail = E - base;
  if (gt < tail){
    int j = base + gt;
    int s0 = fsearch(flist, fn, dp[j]);
    if (s0>=0) l1hit(rel, sp[j], s0, ep[j], w);
  }
}

// K1: blocks [0,scanB) scan Asset-targeting relations for dst == q -> L2 edge
// list. Blocks [scanB, scanB+PFB) stream all weights into the memory-side L3.
__global__ void __launch_bounds__(256) k1(Edges eg, Inputs in, const int* qptr,
                                          WSP w, int scanB){
  if ((int)blockIdx.x >= scanB){
    int gt = (blockIdx.x - scanB)*256 + threadIdx.x, gs = PFB*256;
    float s = 0.f;
    s += pf4(in.Wp_a, 512*128, gt, gs);
    s += pf4(in.Wr1, 6*128*256, gt, gs);
    s += pf4(in.Wl1, 6*128*256, gt, gs);
    s += pf4(in.Wr2, 6*128*128, gt, gs);
    s += pf4(in.Wl2, 6*128*128, gt, gs);
    s += pf4(in.Wc1, 128*128, gt, gs);
    s += pf4(in.We1, 6*256, gt, gs);
    s += pf4(in.att1, 6*256, gt, gs);
    s += pf4(in.bl1, 6*256, gt, gs);
    s += pf4(in.br1, 6*256, gt, gs);
    s += pf4(in.bias1, 6*128, gt, gs);
    s += pf4(in.We2, 6*128, gt, gs);
    s += pf4(in.att2, 6*128, gt, gs);
    s += pf4(in.bias2, 6*128, gt, gs);
    s += pf4(in.bl2, 6*128, gt, gs);
    s += pf4(in.br2, 6*128, gt, gs);
    s += pf4(in.Wc2, 128*3, gt, gs);
    s += pf4(in.bc1, 128, gt, gs);
    asm volatile("" :: "v"(s));   // keep the prefetch loads live (rule #17)
    return;
  }
  int q = qptr[0];
  int gt = blockIdx.x*256 + threadIdx.x, gs = scanB*256;
  l2scan_rel(2, eg.sim_s, eg.sim_d, eg.ea_sim, eg.Esim, q, gt, gs, w);
  l2scan_rel(3, eg.fw_s,  eg.fw_d,  eg.ea_fw,  eg.Efw,  q, gt, gs, w);
  l2scan_rel(4, eg.rcb_s, eg.rcb_d, eg.ea_rcb, eg.Ercb, q, gt, gs, w);
  l2scan_rel(5, eg.rlt_s, eg.rlt_d, eg.ea_rlt, eg.Erlt, q, gt, gs, w);
}

// K2: every block dedups the L2 list into LDS frontier lists (deterministic,
// identical across blocks). Blocks [0,PROJB): project frontier node b and
// precompute its xr1 vectors. Blocks [PROJB, PROJB+SCANB): scan all 6
// relations for dst-in-frontier -> L1 edge list. Both run concurrently.
__global__ void __launch_bounds__(256) k2(Inputs in, Edges eg, WSP w, const int* qptr){
  __shared__ float xs[512], part[256], h0[128];
  __shared__ int s_fa[FAMAX], s_fc[FCMAX], s_fl[FLMAX];
  __shared__ int s_nf[3];
  __shared__ int s_l2rel[N2MAX], s_l2src[N2MAX], s_l2slot[N2MAX];
  int b = blockIdx.x, t = threadIdx.x;
  int q = qptr[0];
  int n2 = min(w.cnt[0], N2MAX);
  for (int i=t; i<n2; i+=256){ s_l2rel[i]=w.l2rel[i]; s_l2src[i]=w.l2src[i]; }
  __syncthreads();
  if (t==0){
    int nfa=0,nfc=0,nfl=0;
    s_fa[nfa++]=q;                      // q is always asset slot 0
    for (int i=0;i<n2;i++){
      int rel=s_l2rel[i], src=s_l2src[i], s=-1;
      if (rel<=3){ s=fsearch(s_fa,nfa,src); if (s<0 && nfa<FAMAX){ s=nfa; s_fa[nfa++]=src; } }
      else if (rel==4){ s=fsearch(s_fc,nfc,src); if (s<0 && nfc<FCMAX){ s=nfc; s_fc[nfc++]=src; } }
      else { s=fsearch(s_fl,nfl,src); if (s<0 && nfl<FLMAX){ s=nfl; s_fl[nfl++]=src; } }
      s_l2slot[i]=s;                    // -1 on frontier-capacity overflow
    }
    s_nf[0]=nfa; s_nf[1]=nfc; s_nf[2]=nfl;
    if (b==0){
      w.nf[0]=nfa; w.nf[1]=nfc; w.nf[2]=nfl;
      for (int i=0;i<n2;i++) w.l2slot[i]=s_l2slot[i];
    }
  }
  __syncthreads();
  int nfa=s_nf[0], nfc=s_nf[1], nfl=s_nf[2];
  if (b < PROJB){
    int nf = nfa+nfc+nfl;
    if (b < nf){
      int type, slot, node;
      if (b<nfa){ type=0; slot=b; node=s_fa[slot]; }
      else if (b<nfa+nfc){ type=1; slot=b-nfa; node=s_fc[slot]; }
      else { type=2; slot=b-nfa-nfc; node=s_fl[slot]; }
      proj256(type, node, in, h0, xs, part);
      if (type==0){
        for (int rr=0; rr<4; rr++){
          int r = 2+rr;
          float acc = in.br1[r*256+t];
          const float* W = in.Wr1 + (size_t)r*128*256 + t;
          for (int c=0;c<128;c++) acc = fmaf(h0[c], W[(size_t)c*256], acc);
          w.xr1a[((size_t)slot*4+rr)*256 + t] = acc;
        }
      } else if (type==1){
        float acc = in.br1[t];
        const float* W = in.Wr1 + t;
        for (int c=0;c<128;c++) acc = fmaf(h0[c], W[(size_t)c*256], acc);
        w.xr1c[(size_t)slot*256+t] = acc;
      } else {
        float acc = in.br1[256+t];
        const float* W = in.Wr1 + (size_t)128*256 + t;
        for (int c=0;c<128;c++) acc = fmaf(h0[c], W[(size_t)c*256], acc);
        w.xr1l[(size_t)slot*256+t] = acc;
      }
    }
    return;
  }
  int gt = (b-PROJB)*256 + t, gs = SCANB*256;
  l1scan_rel(0, eg.cb_s,  eg.cb_d,  eg.ea_cb,  eg.Ecb,  s_fc, nfc, gt, gs, w);
  l1scan_rel(1, eg.lt_s,  eg.lt_d,  eg.ea_lt,  eg.Elt,  s_fl, nfl, gt, gs, w);
  l1scan_rel(2, eg.sim_s, eg.sim_d, eg.ea_sim, eg.Esim, s_fa, nfa, gt, gs, w);
  l1scan_rel(3, eg.fw_s,  eg.fw_d,  eg.ea_fw,  eg.Efw,  s_fa, nfa, gt, gs, w);
  l1scan_rel(4, eg.rcb_s, eg.rcb_d, eg.ea_rcb, eg.Ercb, s_fa, nfa, gt, gs, w);
  l1scan_rel(5, eg.rlt_s, eg.rlt_d, eg.ea_rlt, eg.Erlt, s_fa, nfa, gt, gs, w);
}

// K3: per L1 edge (256 threads): proj(src) -> xl1 (stored), read precomputed
// xr1, attention logits via wave shuffle reduce.
__global__ void __launch_bounds__(256) k3(Inputs in, WSP w){
  __shared__ float xs[512], part[256], h0[128];
  __shared__ float pr[4];
  int t = threadIdx.x;
  int n1 = min(w.cnt[4], N1MAX);
  for (int e = blockIdx.x; e < n1; e += gridDim.x){
    int rel = w.l1rel[e], src = w.l1src[e], dslot = w.l1dslot[e];
    float ea = w.l1ea[e];
    int stype = (rel<=3)?0:(rel==4?1:2);
    proj256(stype, src, in, h0, xs, part);
    float xl1 = in.bl1[rel*256+t];
    {
      const float* W = in.Wl1 + (size_t)rel*128*256 + t;
      for (int c=0;c<128;c++) xl1 = fmaf(h0[c], W[(size_t)c*256], xl1);
    }
    w.xl1e[(size_t)e*256+t] = xl1;
    float xr1 = (rel==0) ? w.xr1c[(size_t)dslot*256+t]
              : (rel==1) ? w.xr1l[(size_t)dslot*256+t]
              : w.xr1a[((size_t)dslot*4 + (rel-2))*256 + t];
    float ev = leaky(xl1 + xr1 + ea*in.We1[rel*256+t]);
    float rd = ev * in.att1[(rel*2 + (t>>7))*128 + (t&127)];
    for (int off=32; off; off>>=1) rd += __shfl_down(rd, off);
    if ((t&63)==0) pr[t>>6] = rd;
    __syncthreads();
    if (t==0){ w.logit1[2*e]=pr[0]+pr[1]; w.logit1[2*e+1]=pr[2]+pr[3]; }
    __syncthreads();
  }
}

// K45: one block per L2 edge (N2MAX blocks, 256 threads). Each block:
// (1) aggregates layer-1 output for q AND its src node fully in LDS
//     (filter n1 edges -> per-rel lists -> segment softmax + agg),
// (2) xr2/xl2 GEMVs split-K by 2 + attention logit.
// Last-finishing block (device-scope ticket) runs the layer-2 segment
// softmax + classifier head.
__global__ void __launch_bounds__(256) k45(Inputs in, WSP w, float* outp){
  __shared__ int   s_key[N1MAX];
  __shared__ float s_lg0[N1MAX], s_lg1[N1MAX];
  __shared__ int   s_lq[4][N1MAX], s_ls[4][N1MAX];
  __shared__ int   s_c[8];
  __shared__ float sA[256];
  __shared__ float xq[128], xsrc[128];
  __shared__ float px[256], pl[256];
  __shared__ float pr[2];
  __shared__ int   s_last;
  int e = blockIdx.x, t = threadIdx.x;
  int n2 = min(w.cnt[0], N2MAX);
  bool active = (e < n2);
  int rel = 2, slot = -1; float ea = 0.f;
  if (active){ rel = w.l2rel[e]; slot = w.l2slot[e]; ea = w.l2ea[e]; }
  if (active && slot >= 0){
    int n1 = min(w.cnt[4], N1MAX);
    if (t<8) s_c[t]=0;
    __syncthreads();
    for (int i=t;i<n1;i+=256){
      s_key[i] = (w.l1rel[i]<<6) | w.l1dslot[i];
      float2 L = ((const float2*)w.logit1)[i];
      s_lg0[i]=L.x; s_lg1[i]=L.y;
    }
    __syncthreads();
    int sr0 = (rel<=3)?2:(rel==4?0:1);
    int snr = (rel<=3)?4:1;
    bool srcq = (rel<=3 && slot==0);   // src IS q
    for (int i=t;i<n1;i+=256){
      int key=s_key[i], r=key>>6, sl=key&63;
      if (sl==0 && r>=2){ int p=atomicAdd(&s_c[r-2],1); s_lq[r-2][p]=i; }
      if (!srcq && sl==slot && r>=sr0 && r<sr0+snr){
        int p=atomicAdd(&s_c[4+r-sr0],1); s_ls[r-sr0][p]=i;
      }
    }
    __syncthreads();
    int j=t&127, h=t>>7;
    const float* lg = h ? s_lg1 : s_lg0;
    {  // ---- q aggregation (asset, rels 2..5, slot 0) ----
      float out=0.f;
      for (int ri=0;ri<4;ri++){
        int r=2+ri, c=s_c[ri];
        float av=0.f;
        if (c>0){
          const int* lst=s_lq[ri];
          float m=-INFINITY;
          for (int o=0;o<c;o++) m=fmaxf(m, lg[lst[o]]);
          float d=0.f,a=0.f;
          for (int o=0;o<c;o++){
            int i=lst[o];
            float ex=expf(lg[i]-m);
            d+=ex;
            a=fmaf(ex, w.xl1e[(size_t)i*256 + h*128 + j], a);
          }
          av=a/(d+1e-16f);
        }
        sA[t]=av; __syncthreads();
        if (t<128) out += in.bias1[r*128+j] + 0.5f*(sA[j]+sA[j+128]);
        __syncthreads();
      }
      if (t<128) xq[j]=fmaxf(out,0.f);
      __syncthreads();
    }
    if (srcq){
      if (t<128) xsrc[t]=xq[t];
      __syncthreads();
    } else {  // ---- src aggregation ----
      float out=0.f;
      for (int ri=0;ri<snr;ri++){
        int r=sr0+ri, c=s_c[4+ri];
        float av=0.f;
        if (c>0){
          const int* lst=s_ls[ri];
          float m=-INFINITY;
          for (int o=0;o<c;o++) m=fmaxf(m, lg[lst[o]]);
          float d=0.f,a=0.f;
          for (int o=0;o<c;o++){
            int i=lst[o];
            float ex=expf(lg[i]-m);
            d+=ex;
            a=fmaf(ex, w.xl1e[(size_t)i*256 + h*128 + j], a);
          }
          av=a/(d+1e-16f);
        }
        sA[t]=av; __syncthreads();
        if (t<128) out += in.bias1[r*128+j] + 0.5f*(sA[j]+sA[j+128]);
        __syncthreads();
      }
      if (t<128) xsrc[j]=fmaxf(out,0.f);
      __syncthreads();
    }
    // ---- xr2/xl2 GEMVs (split-K by 2) + logit ----
    int g=t>>7;
    float axr=0.f, axl=0.f;
    {
      const float* Wr = in.Wr2 + (size_t)rel*128*128 + j;
      const float* Wl = in.Wl2 + (size_t)rel*128*128 + j;
      for (int c=g*64;c<g*64+64;c++){
        axr=fmaf(xq[c],   Wr[(size_t)c*128], axr);
        axl=fmaf(xsrc[c], Wl[(size_t)c*128], axl);
      }
    }
    px[t]=axr; pl[t]=axl;
    __syncthreads();
    float rd=0.f;
    if (t<128){
      float xr2 = in.br2[rel*128+j] + px[j] + px[j+128];
      float xl2 = in.bl2[rel*128+j] + pl[j] + pl[j+128];
      w.xl2e[(size_t)e*128+j]=xl2;
      float ev = leaky(xl2 + xr2 + ea*in.We2[rel*128+j]);
      rd = ev * in.att2[rel*128+j];
    }
    for (int off=32;off;off>>=1) rd += __shfl_down(rd,off);
    if ((t&63)==0 && t<128) pr[t>>6]=rd;
    __syncthreads();
    if (t==0) w.logit2[e]=pr[0]+pr[1];
  } else if (active){   // frontier-capacity overflow guard
    if (t<128) w.xl2e[(size_t)e*128+t]=0.f;
    if (t==0) w.logit2[e]=-INFINITY;
  }
  // ---- ticket: last block runs layer-2 softmax + classifier ----
  __syncthreads();
  if (t==0){
    __threadfence();                         // release: drain our stores
    int v = atomicAdd(&w.cnt[12], 1);
    s_last = (v == (int)gridDim.x - 1) ? 1 : 0;
  }
  __syncthreads();
  if (!s_last) return;
  if (t==0) __threadfence();                 // acquire: invalidate stale caches
  __syncthreads();
  for (int i=t;i<n2;i+=256){ s_key[i]=w.l2rel[i]; s_lg0[i]=w.logit2[i]; }
  __syncthreads();
  if (t<128){
    float o=0.f;
    for (int r=2;r<=5;r++){
      o += in.bias2[r*128+t];
      float m=-INFINITY;
      for (int i=0;i<n2;i++) if (s_key[i]==r) m=fmaxf(m,s_lg0[i]);
      if (m==-INFINITY) continue;
      float d=0.f, acc=0.f;
      for (int i=0;i<n2;i++) if (s_key[i]==r){
        float ex=expf(s_lg0[i]-m);
        d+=ex;
        acc=fmaf(ex, w.xl2e[(size_t)i*128+t], acc);
      }
      o += acc/(d+1e-16f);
    }
    xq[t]=fmaxf(o,0.f);                       // x2
  }
  __syncthreads();
  int j=t&127, g=t>>7;
  float a=0.f;
  for (int c=g*64;c<g*64+64;c++) a=fmaf(xq[c], in.Wc1[(size_t)c*128+j], a);
  px[t]=a;
  __syncthreads();
  if (t<128) xsrc[t]=fmaxf(in.bc1[t]+px[t]+px[t+128], 0.f);   // hidden
  __syncthreads();
  if (t<3){
    float r=in.bc2[t];
    for (int c=0;c<128;c++) r=fmaf(xsrc[c], in.Wc2[c*3+t], r);
    outp[t]=r;
  }
}

extern "C" void kernel_launch(void* const* d_in, const int* in_sizes, int n_in,
                              void* d_out, int out_size, void* d_ws, size_t ws_size,
                              hipStream_t stream){
  Inputs in;
  in.x_asset   = (const float*)d_in[0];
  in.x_creator = (const float*)d_in[1];
  in.x_licensee= (const float*)d_in[2];
  Edges eg;
  eg.cb_s =(const int*)d_in[3];  eg.cb_d =(const int*)d_in[4];  eg.ea_cb =(const float*)d_in[5];  eg.Ecb = in_sizes[3];
  eg.lt_s =(const int*)d_in[6];  eg.lt_d =(const int*)d_in[7];  eg.ea_lt =(const float*)d_in[8];  eg.Elt = in_sizes[6];
  eg.sim_s=(const int*)d_in[9];  eg.sim_d=(const int*)d_in[10]; eg.ea_sim=(const float*)d_in[11]; eg.Esim= in_sizes[9];
  eg.fw_s =(const int*)d_in[12]; eg.fw_d =(const int*)d_in[13]; eg.ea_fw =(const float*)d_in[14]; eg.Efw = in_sizes[12];
  eg.rcb_s=(const int*)d_in[15]; eg.rcb_d=(const int*)d_in[16]; eg.ea_rcb=(const float*)d_in[17]; eg.Ercb= in_sizes[15];
  eg.rlt_s=(const int*)d_in[18]; eg.rlt_d=(const int*)d_in[19]; eg.ea_rlt=(const float*)d_in[20]; eg.Erlt= in_sizes[18];
  in.Wp_a=(const float*)d_in[21]; in.bp_a=(const float*)d_in[22];
  in.Wp_c=(const float*)d_in[23]; in.bp_c=(const float*)d_in[24];
  in.Wp_l=(const float*)d_in[25]; in.bp_l=(const float*)d_in[26];
  in.Wl1=(const float*)d_in[27]; in.bl1=(const float*)d_in[28];
  in.Wr1=(const float*)d_in[29]; in.br1=(const float*)d_in[30];
  in.We1=(const float*)d_in[31]; in.att1=(const float*)d_in[32]; in.bias1=(const float*)d_in[33];
  in.Wl2=(const float*)d_in[34]; in.bl2=(const float*)d_in[35];
  in.Wr2=(const float*)d_in[36]; in.br2=(const float*)d_in[37];
  in.We2=(const float*)d_in[38]; in.att2=(const float*)d_in[39]; in.bias2=(const float*)d_in[40];
  in.Wc1=(const float*)d_in[41]; in.bc1=(const float*)d_in[42];
  in.Wc2=(const float*)d_in[43]; in.bc2=(const float*)d_in[44];
  const int* qptr = (const int*)d_in[45];
  float* outp = (float*)d_out;

  char* p = (char*)d_ws;
  auto carve = [&](size_t n)->char*{ char* r = p; p += ((n + 255) & ~(size_t)255); return r; };
  WSP w;
  w.cnt  = (int*)carve(16*4);
  w.nf   = (int*)carve(3*4);
  w.l2rel=(int*)carve(N2MAX*4); w.l2src=(int*)carve(N2MAX*4);
  w.l2ea=(float*)carve(N2MAX*4); w.l2slot=(int*)carve(N2MAX*4);
  w.l1rel=(int*)carve(N1MAX*4); w.l1src=(int*)carve(N1MAX*4);
  w.l1dslot=(int*)carve(N1MAX*4); w.l1ea=(float*)carve(N1MAX*4);
  w.xr1a=(float*)carve((size_t)FAMAX*4*256*4);
  w.xr1c=(float*)carve((size_t)FCMAX*256*4);
  w.xr1l=(float*)carve((size_t)FLMAX*256*4);
  w.xl1e=(float*)carve((size_t)N1MAX*256*4);
  w.logit1=(float*)carve((size_t)N1MAX*2*4);
  w.xl2e=(float*)carve((size_t)N2MAX*128*4);
  w.logit2=(float*)carve(N2MAX*4);

  hipMemsetAsync(w.cnt, 0, 64, stream);   // counters + k45 ticket

  int quad2 = (eg.Esim + eg.Efw + eg.Ercb + eg.Erlt)/4 + 1;
  int b1 = (quad2 + 255)/256; if (b1 > 1024) b1 = 1024;
  k1<<<b1 + PFB, 256, 0, stream>>>(eg, in, qptr, w, b1);
  k2<<<PROJB + SCANB, 256, 0, stream>>>(in, eg, w, qptr);
  k3<<<256, 256, 0, stream>>>(in, w);
  k45<<<N2MAX, 256, 0, stream>>>(in, w, outp);
}

// Round 9
// 280.679 us; speedup vs baseline: 2.1912x; 1.0213x over previous
//
#include <hip/hip_runtime.h>
#include <math.h>

// R15: R14 + extended k1 prefetch. k2's L1 scan was reading cb_d/lt_d
// (600 KB) cold-HBM, and k2/k3's creator/licensee projections first-touched
// x_creator/x_licensee (120 KB). Add all four to k1's L3-warming list so the
// entire downstream chain runs L3-warm. Everything else identical to R14
// (chain: memset -> k1 scan+prefetch -> k2 dedup+proj||scan -> k3 -> k45).
#define FAMAX 64     // dst-frontier assets (expected ~11)
#define FCMAX 32     // dst-frontier creators (expected ~1)
#define FLMAX 32     // dst-frontier licensees (expected ~2)
#define N1MAX 512    // layer-1 edges into frontier (expected ~125)
#define N2MAX 128    // layer-2 edges into query (expected ~9)
#define PROJB 128    // k2 blocks reserved for frontier projections
#define SCANB 512    // k2 blocks doing the L1 edge scan
#define PFB   96     // k1 prefetch blocks

struct Inputs {
  const float *x_asset, *x_creator, *x_licensee;
  const float *Wp_a,*bp_a,*Wp_c,*bp_c,*Wp_l,*bp_l;
  const float *Wl1,*bl1,*Wr1,*br1,*We1,*att1,*bias1;
  const float *Wl2,*bl2,*Wr2,*br2,*We2,*att2,*bias2;
  const float *Wc1,*bc1,*Wc2,*bc2;
};

struct Edges {
  const int *cb_s,*cb_d;  const float* ea_cb;  int Ecb;
  const int *lt_s,*lt_d;  const float* ea_lt;  int Elt;
  const int *sim_s,*sim_d;const float* ea_sim; int Esim;
  const int *fw_s,*fw_d;  const float* ea_fw;  int Efw;
  const int *rcb_s,*rcb_d;const float* ea_rcb; int Ercb;
  const int *rlt_s,*rlt_d;const float* ea_rlt; int Erlt;
};

struct WSP {
  int* cnt;             // [0]=n_l2e [4]=n_l1e [12]=k45 ticket (zeroed by 64B memset)
  int* nf;              // [3] frontier counts (written by k2 block 0)
  int* l2rel; int* l2src; float* l2ea; int* l2slot;
  int* l1rel; int* l1src; int* l1dslot; float* l1ea;
  float* xr1a;          // [FAMAX][4][256]  dst-side xr1 for asset nodes, rels 2..5
  float* xr1c;          // [FCMAX][256]     rel 0
  float* xr1l;          // [FLMAX][256]     rel 1
  float* xl1e;          // [N1MAX][256]
  float* logit1;        // [N1MAX][2]
  float* xl2e;          // [N2MAX][128]
  float* logit2;        // [N2MAX]
};

__device__ __forceinline__ float leaky(float x){ return x > 0.f ? x : 0.2f*x; }

__device__ __forceinline__ int fsearch(const int* list, int n, int v){
  for (int k=0;k<n;k++) if (list[k]==v) return k;
  return -1;
}

// sum n floats (n%4==0) with float4 loads — L3 warmer, result kept live
// by the caller's asm sink.
__device__ __forceinline__ float pf4(const float* p, int n, int gt, int gs){
  float s = 0.f;
  const float4* p4 = (const float4*)p;
  int n4 = n >> 2;
  for (int i = gt; i < n4; i += gs){ float4 v = p4[i]; s += v.x+v.y+v.z+v.w; }
  return s;
}

// 128-d projection of `node` of `type` into LDS h0[] using 256 threads.
__device__ __forceinline__ void proj256(int type, int node, const Inputs& in,
                                        float* h0, float* xs, float* part){
  int t = threadIdx.x;
  if (type == 0){
    xs[t]       = in.x_asset[(size_t)node*512 + t];
    xs[t + 256] = in.x_asset[(size_t)node*512 + t + 256];
    __syncthreads();
    int j = t & 127, g2 = t >> 7;
    float acc = 0.f;
    const float* W = in.Wp_a + (size_t)g2*256*128 + j;
    const float* xg = xs + g2*256;
    for (int k=0;k<256;k++) acc = fmaf(xg[k], W[(size_t)k*128], acc);
    part[t] = acc;
    __syncthreads();
    if (t < 128) h0[t] = in.bp_a[t] + part[t] + part[128 + t];
  } else if (type == 1){
    if (t < 128)
      h0[t] = in.bp_c[t] + in.x_creator[node*2]*in.Wp_c[t]
            + in.x_creator[node*2+1]*in.Wp_c[128+t];
  } else {
    if (t < 128)
      h0[t] = in.bp_l[t] + in.x_licensee[node]*in.Wp_l[t];
  }
  __syncthreads();
}

__device__ __forceinline__ void l2hit(int rel, int s, float e, WSP& w){
  int k = atomicAdd(&w.cnt[0], 1);
  if (k < N2MAX){ w.l2rel[k]=rel; w.l2src[k]=s; w.l2ea[k]=e; }
}

__device__ __forceinline__ void l2scan_rel(int rel, const int* sp, const int* dp,
                                           const float* ep, int E, int q,
                                           int gt, int gs, WSP& w){
  int nq = E >> 2;
  const int4* d4 = (const int4*)dp;
  for (int i = gt; i < nq; i += gs){
    int4 d = d4[i];
    int j = i << 2;
    if (d.x == q) l2hit(rel, sp[j],   ep[j],   w);
    if (d.y == q) l2hit(rel, sp[j+1], ep[j+1], w);
    if (d.z == q) l2hit(rel, sp[j+2], ep[j+2], w);
    if (d.w == q) l2hit(rel, sp[j+3], ep[j+3], w);
  }
  int base = nq << 2, tail = E - base;
  if (gt < tail){
    int j = base + gt;
    if (dp[j] == q) l2hit(rel, sp[j], ep[j], w);
  }
}

__device__ __forceinline__ void l1hit(int rel, int s, int slot, float e, WSP& w){
  int k = atomicAdd(&w.cnt[4], 1);
  if (k < N1MAX){ w.l1rel[k]=rel; w.l1src[k]=s; w.l1dslot[k]=slot; w.l1ea[k]=e; }
}

__device__ __forceinline__ void l1scan_rel(int rel, const int* sp, const int* dp,
                                           const float* ep, int E,
                                           const int* flist, int fn,
                                           int gt, int gs, WSP& w){
  int nq = E >> 2;
  const int4* d4 = (const int4*)dp;
  for (int i = gt; i < nq; i += gs){
    int4 d = d4[i];
    int j = i << 2;
    int s0 = fsearch(flist, fn, d.x); if (s0>=0) l1hit(rel, sp[j],   s0, ep[j],   w);
    int s1 = fsearch(flist, fn, d.y); if (s1>=0) l1hit(rel, sp[j+1], s1, ep[j+1], w);
    int s2 = fsearch(flist, fn, d.z); if (s2>=0) l1hit(rel, sp[j+2], s2, ep[j+2], w);
    int s3 = fsearch(flist, fn, d.w); if (s3>=0) l1hit(rel, sp[j+3], s3, ep[j+3], w);
  }
  int base = nq << 2, tail = E - base;
  if (gt < tail){
    int j = base + gt;
    int s0 = fsearch(flist, fn, dp[j]);
    if (s0>=0) l1hit(rel, sp[j], s0, ep[j], w);
  }
}

// K1: blocks [0,scanB) scan Asset-targeting relations for dst == q -> L2 edge
// list. Blocks [scanB, scanB+PFB) stream all weights + the L1-scan edge
// arrays + small feature tables into the memory-side L3.
__global__ void __launch_bounds__(256) k1(Edges eg, Inputs in, const int* qptr,
                                          WSP w, int scanB){
  if ((int)blockIdx.x >= scanB){
    int gt = (blockIdx.x - scanB)*256 + threadIdx.x, gs = PFB*256;
    float s = 0.f;
    s += pf4(in.Wp_a, 512*128, gt, gs);
    s += pf4(in.Wr1, 6*128*256, gt, gs);
    s += pf4(in.Wl1, 6*128*256, gt, gs);
    s += pf4(in.Wr2, 6*128*128, gt, gs);
    s += pf4(in.Wl2, 6*128*128, gt, gs);
    s += pf4(in.Wc1, 128*128, gt, gs);
    // cold inputs k2/k3 touch that k1's own scan doesn't warm:
    s += pf4((const float*)eg.cb_d, eg.Ecb & ~3, gt, gs);
    s += pf4((const float*)eg.lt_d, eg.Elt & ~3, gt, gs);
    s += pf4(in.x_creator, 10000*2, gt, gs);
    s += pf4(in.x_licensee, 10000, gt, gs);
    s += pf4(in.We1, 6*256, gt, gs);
    s += pf4(in.att1, 6*256, gt, gs);
    s += pf4(in.bl1, 6*256, gt, gs);
    s += pf4(in.br1, 6*256, gt, gs);
    s += pf4(in.bias1, 6*128, gt, gs);
    s += pf4(in.We2, 6*128, gt, gs);
    s += pf4(in.att2, 6*128, gt, gs);
    s += pf4(in.bias2, 6*128, gt, gs);
    s += pf4(in.bl2, 6*128, gt, gs);
    s += pf4(in.br2, 6*128, gt, gs);
    s += pf4(in.Wc2, 128*3, gt, gs);
    s += pf4(in.bc1, 128, gt, gs);
    asm volatile("" :: "v"(s));   // keep the prefetch loads live (rule #17)
    return;
  }
  int q = qptr[0];
  int gt = blockIdx.x*256 + threadIdx.x, gs = scanB*256;
  l2scan_rel(2, eg.sim_s, eg.sim_d, eg.ea_sim, eg.Esim, q, gt, gs, w);
  l2scan_rel(3, eg.fw_s,  eg.fw_d,  eg.ea_fw,  eg.Efw,  q, gt, gs, w);
  l2scan_rel(4, eg.rcb_s, eg.rcb_d, eg.ea_rcb, eg.Ercb, q, gt, gs, w);
  l2scan_rel(5, eg.rlt_s, eg.rlt_d, eg.ea_rlt, eg.Erlt, q, gt, gs, w);
}

// K2: every block dedups the L2 list into LDS frontier lists (deterministic,
// identical across blocks). Blocks [0,PROJB): project frontier node b and
// precompute its xr1 vectors. Blocks [PROJB, PROJB+SCANB): scan all 6
// relations for dst-in-frontier -> L1 edge list. Both run concurrently.
__global__ void __launch_bounds__(256) k2(Inputs in, Edges eg, WSP w, const int* qptr){
  __shared__ float xs[512], part[256], h0[128];
  __shared__ int s_fa[FAMAX], s_fc[FCMAX], s_fl[FLMAX];
  __shared__ int s_nf[3];
  __shared__ int s_l2rel[N2MAX], s_l2src[N2MAX], s_l2slot[N2MAX];
  int b = blockIdx.x, t = threadIdx.x;
  int q = qptr[0];
  int n2 = min(w.cnt[0], N2MAX);
  for (int i=t; i<n2; i+=256){ s_l2rel[i]=w.l2rel[i]; s_l2src[i]=w.l2src[i]; }
  __syncthreads();
  if (t==0){
    int nfa=0,nfc=0,nfl=0;
    s_fa[nfa++]=q;                      // q is always asset slot 0
    for (int i=0;i<n2;i++){
      int rel=s_l2rel[i], src=s_l2src[i], s=-1;
      if (rel<=3){ s=fsearch(s_fa,nfa,src); if (s<0 && nfa<FAMAX){ s=nfa; s_fa[nfa++]=src; } }
      else if (rel==4){ s=fsearch(s_fc,nfc,src); if (s<0 && nfc<FCMAX){ s=nfc; s_fc[nfc++]=src; } }
      else { s=fsearch(s_fl,nfl,src); if (s<0 && nfl<FLMAX){ s=nfl; s_fl[nfl++]=src; } }
      s_l2slot[i]=s;                    // -1 on frontier-capacity overflow
    }
    s_nf[0]=nfa; s_nf[1]=nfc; s_nf[2]=nfl;
    if (b==0){
      w.nf[0]=nfa; w.nf[1]=nfc; w.nf[2]=nfl;
      for (int i=0;i<n2;i++) w.l2slot[i]=s_l2slot[i];
    }
  }
  __syncthreads();
  int nfa=s_nf[0], nfc=s_nf[1], nfl=s_nf[2];
  if (b < PROJB){
    int nf = nfa+nfc+nfl;
    if (b < nf){
      int type, slot, node;
      if (b<nfa){ type=0; slot=b; node=s_fa[slot]; }
      else if (b<nfa+nfc){ type=1; slot=b-nfa; node=s_fc[slot]; }
      else { type=2; slot=b-nfa-nfc; node=s_fl[slot]; }
      proj256(type, node, in, h0, xs, part);
      if (type==0){
        for (int rr=0; rr<4; rr++){
          int r = 2+rr;
          float acc = in.br1[r*256+t];
          const float* W = in.Wr1 + (size_t)r*128*256 + t;
          for (int c=0;c<128;c++) acc = fmaf(h0[c], W[(size_t)c*256], acc);
          w.xr1a[((size_t)slot*4+rr)*256 + t] = acc;
        }
      } else if (type==1){
        float acc = in.br1[t];
        const float* W = in.Wr1 + t;
        for (int c=0;c<128;c++) acc = fmaf(h0[c], W[(size_t)c*256], acc);
        w.xr1c[(size_t)slot*256+t] = acc;
      } else {
        float acc = in.br1[256+t];
        const float* W = in.Wr1 + (size_t)128*256 + t;
        for (int c=0;c<128;c++) acc = fmaf(h0[c], W[(size_t)c*256], acc);
        w.xr1l[(size_t)slot*256+t] = acc;
      }
    }
    return;
  }
  int gt = (b-PROJB)*256 + t, gs = SCANB*256;
  l1scan_rel(0, eg.cb_s,  eg.cb_d,  eg.ea_cb,  eg.Ecb,  s_fc, nfc, gt, gs, w);
  l1scan_rel(1, eg.lt_s,  eg.lt_d,  eg.ea_lt,  eg.Elt,  s_fl, nfl, gt, gs, w);
  l1scan_rel(2, eg.sim_s, eg.sim_d, eg.ea_sim, eg.Esim, s_fa, nfa, gt, gs, w);
  l1scan_rel(3, eg.fw_s,  eg.fw_d,  eg.ea_fw,  eg.Efw,  s_fa, nfa, gt, gs, w);
  l1scan_rel(4, eg.rcb_s, eg.rcb_d, eg.ea_rcb, eg.Ercb, s_fa, nfa, gt, gs, w);
  l1scan_rel(5, eg.rlt_s, eg.rlt_d, eg.ea_rlt, eg.Erlt, s_fa, nfa, gt, gs, w);
}

// K3: per L1 edge (256 threads): proj(src) -> xl1 (stored), read precomputed
// xr1, attention logits via wave shuffle reduce.
__global__ void __launch_bounds__(256) k3(Inputs in, WSP w){
  __shared__ float xs[512], part[256], h0[128];
  __shared__ float pr[4];
  int t = threadIdx.x;
  int n1 = min(w.cnt[4], N1MAX);
  for (int e = blockIdx.x; e < n1; e += gridDim.x){
    int rel = w.l1rel[e], src = w.l1src[e], dslot = w.l1dslot[e];
    float ea = w.l1ea[e];
    int stype = (rel<=3)?0:(rel==4?1:2);
    proj256(stype, src, in, h0, xs, part);
    float xl1 = in.bl1[rel*256+t];
    {
      const float* W = in.Wl1 + (size_t)rel*128*256 + t;
      for (int c=0;c<128;c++) xl1 = fmaf(h0[c], W[(size_t)c*256], xl1);
    }
    w.xl1e[(size_t)e*256+t] = xl1;
    float xr1 = (rel==0) ? w.xr1c[(size_t)dslot*256+t]
              : (rel==1) ? w.xr1l[(size_t)dslot*256+t]
              : w.xr1a[((size_t)dslot*4 + (rel-2))*256 + t];
    float ev = leaky(xl1 + xr1 + ea*in.We1[rel*256+t]);
    float rd = ev * in.att1[(rel*2 + (t>>7))*128 + (t&127)];
    for (int off=32; off; off>>=1) rd += __shfl_down(rd, off);
    if ((t&63)==0) pr[t>>6] = rd;
    __syncthreads();
    if (t==0){ w.logit1[2*e]=pr[0]+pr[1]; w.logit1[2*e+1]=pr[2]+pr[3]; }
    __syncthreads();
  }
}

// K45: one block per L2 edge (N2MAX blocks, 256 threads). Each block:
// (1) aggregates layer-1 output for q AND its src node fully in LDS
//     (filter n1 edges -> per-rel lists -> segment softmax + agg),
// (2) xr2/xl2 GEMVs split-K by 2 + attention logit.
// Last-finishing block (device-scope ticket) runs the layer-2 segment
// softmax + classifier head.
__global__ void __launch_bounds__(256) k45(Inputs in, WSP w, float* outp){
  __shared__ int   s_key[N1MAX];
  __shared__ float s_lg0[N1MAX], s_lg1[N1MAX];
  __shared__ int   s_lq[4][N1MAX], s_ls[4][N1MAX];
  __shared__ int   s_c[8];
  __shared__ float sA[256];
  __shared__ float xq[128], xsrc[128];
  __shared__ float px[256], pl[256];
  __shared__ float pr[2];
  __shared__ int   s_last;
  int e = blockIdx.x, t = threadIdx.x;
  int n2 = min(w.cnt[0], N2MAX);
  bool active = (e < n2);
  int rel = 2, slot = -1; float ea = 0.f;
  if (active){ rel = w.l2rel[e]; slot = w.l2slot[e]; ea = w.l2ea[e]; }
  if (active && slot >= 0){
    int n1 = min(w.cnt[4], N1MAX);
    if (t<8) s_c[t]=0;
    __syncthreads();
    for (int i=t;i<n1;i+=256){
      s_key[i] = (w.l1rel[i]<<6) | w.l1dslot[i];
      float2 L = ((const float2*)w.logit1)[i];
      s_lg0[i]=L.x; s_lg1[i]=L.y;
    }
    __syncthreads();
    int sr0 = (rel<=3)?2:(rel==4?0:1);
    int snr = (rel<=3)?4:1;
    bool srcq = (rel<=3 && slot==0);   // src IS q
    for (int i=t;i<n1;i+=256){
      int key=s_key[i], r=key>>6, sl=key&63;
      if (sl==0 && r>=2){ int p=atomicAdd(&s_c[r-2],1); s_lq[r-2][p]=i; }
      if (!srcq && sl==slot && r>=sr0 && r<sr0+snr){
        int p=atomicAdd(&s_c[4+r-sr0],1); s_ls[r-sr0][p]=i;
      }
    }
    __syncthreads();
    int j=t&127, h=t>>7;
    const float* lg = h ? s_lg1 : s_lg0;
    {  // ---- q aggregation (asset, rels 2..5, slot 0) ----
      float out=0.f;
      for (int ri=0;ri<4;ri++){
        int r=2+ri, c=s_c[ri];
        float av=0.f;
        if (c>0){
          const int* lst=s_lq[ri];
          float m=-INFINITY;
          for (int o=0;o<c;o++) m=fmaxf(m, lg[lst[o]]);
          float d=0.f,a=0.f;
          for (int o=0;o<c;o++){
            int i=lst[o];
            float ex=expf(lg[i]-m);
            d+=ex;
            a=fmaf(ex, w.xl1e[(size_t)i*256 + h*128 + j], a);
          }
          av=a/(d+1e-16f);
        }
        sA[t]=av; __syncthreads();
        if (t<128) out += in.bias1[r*128+j] + 0.5f*(sA[j]+sA[j+128]);
        __syncthreads();
      }
      if (t<128) xq[j]=fmaxf(out,0.f);
      __syncthreads();
    }
    if (srcq){
      if (t<128) xsrc[t]=xq[t];
      __syncthreads();
    } else {  // ---- src aggregation ----
      float out=0.f;
      for (int ri=0;ri<snr;ri++){
        int r=sr0+ri, c=s_c[4+ri];
        float av=0.f;
        if (c>0){
          const int* lst=s_ls[ri];
          float m=-INFINITY;
          for (int o=0;o<c;o++) m=fmaxf(m, lg[lst[o]]);
          float d=0.f,a=0.f;
          for (int o=0;o<c;o++){
            int i=lst[o];
            float ex=expf(lg[i]-m);
            d+=ex;
            a=fmaf(ex, w.xl1e[(size_t)i*256 + h*128 + j], a);
          }
          av=a/(d+1e-16f);
        }
        sA[t]=av; __syncthreads();
        if (t<128) out += in.bias1[r*128+j] + 0.5f*(sA[j]+sA[j+128]);
        __syncthreads();
      }
      if (t<128) xsrc[j]=fmaxf(out,0.f);
      __syncthreads();
    }
    // ---- xr2/xl2 GEMVs (split-K by 2) + logit ----
    int g=t>>7;
    float axr=0.f, axl=0.f;
    {
      const float* Wr = in.Wr2 + (size_t)rel*128*128 + j;
      const float* Wl = in.Wl2 + (size_t)rel*128*128 + j;
      for (int c=g*64;c<g*64+64;c++){
        axr=fmaf(xq[c],   Wr[(size_t)c*128], axr);
        axl=fmaf(xsrc[c], Wl[(size_t)c*128], axl);
      }
    }
    px[t]=axr; pl[t]=axl;
    __syncthreads();
    float rd=0.f;
    if (t<128){
      float xr2 = in.br2[rel*128+j] + px[j] + px[j+128];
      float xl2 = in.bl2[rel*128+j] + pl[j] + pl[j+128];
      w.xl2e[(size_t)e*128+j]=xl2;
      float ev = leaky(xl2 + xr2 + ea*in.We2[rel*128+j]);
      rd = ev * in.att2[rel*128+j];
    }
    for (int off=32;off;off>>=1) rd += __shfl_down(rd,off);
    if ((t&63)==0 && t<128) pr[t>>6]=rd;
    __syncthreads();
    if (t==0) w.logit2[e]=pr[0]+pr[1];
  } else if (active){   // frontier-capacity overflow guard
    if (t<128) w.xl2e[(size_t)e*128+t]=0.f;
    if (t==0) w.logit2[e]=-INFINITY;
  }
  // ---- ticket: last block runs layer-2 softmax + classifier ----
  __syncthreads();
  if (t==0){
    __threadfence();                         // release: drain our stores
    int v = atomicAdd(&w.cnt[12], 1);
    s_last = (v == (int)gridDim.x - 1) ? 1 : 0;
  }
  __syncthreads();
  if (!s_last) return;
  if (t==0) __threadfence();                 // acquire: invalidate stale caches
  __syncthreads();
  for (int i=t;i<n2;i+=256){ s_key[i]=w.l2rel[i]; s_lg0[i]=w.logit2[i]; }
  __syncthreads();
  if (t<128){
    float o=0.f;
    for (int r=2;r<=5;r++){
      o += in.bias2[r*128+t];
      float m=-INFINITY;
      for (int i=0;i<n2;i++) if (s_key[i]==r) m=fmaxf(m,s_lg0[i]);
      if (m==-INFINITY) continue;
      float d=0.f, acc=0.f;
      for (int i=0;i<n2;i++) if (s_key[i]==r){
        float ex=expf(s_lg0[i]-m);
        d+=ex;
        acc=fmaf(ex, w.xl2e[(size_t)i*128+t], acc);
      }
      o += acc/(d+1e-16f);
    }
    xq[t]=fmaxf(o,0.f);                       // x2
  }
  __syncthreads();
  int j=t&127, g=t>>7;
  float a=0.f;
  for (int c=g*64;c<g*64+64;c++) a=fmaf(xq[c], in.Wc1[(size_t)c*128+j], a);
  px[t]=a;
  __syncthreads();
  if (t<128) xsrc[t]=fmaxf(in.bc1[t]+px[t]+px[t+128], 0.f);   // hidden
  __syncthreads();
  if (t<3){
    float r=in.bc2[t];
    for (int c=0;c<128;c++) r=fmaf(xsrc[c], in.Wc2[c*3+t], r);
    outp[t]=r;
  }
}

extern "C" void kernel_launch(void* const* d_in, const int* in_sizes, int n_in,
                              void* d_out, int out_size, void* d_ws, size_t ws_size,
                              hipStream_t stream){
  Inputs in;
  in.x_asset   = (const float*)d_in[0];
  in.x_creator = (const float*)d_in[1];
  in.x_licensee= (const float*)d_in[2];
  Edges eg;
  eg.cb_s =(const int*)d_in[3];  eg.cb_d =(const int*)d_in[4];  eg.ea_cb =(const float*)d_in[5];  eg.Ecb = in_sizes[3];
  eg.lt_s =(const int*)d_in[6];  eg.lt_d =(const int*)d_in[7];  eg.ea_lt =(const float*)d_in[8];  eg.Elt = in_sizes[6];
  eg.sim_s=(const int*)d_in[9];  eg.sim_d=(const int*)d_in[10]; eg.ea_sim=(const float*)d_in[11]; eg.Esim= in_sizes[9];
  eg.fw_s =(const int*)d_in[12]; eg.fw_d =(const int*)d_in[13]; eg.ea_fw =(const float*)d_in[14]; eg.Efw = in_sizes[12];
  eg.rcb_s=(const int*)d_in[15]; eg.rcb_d=(const int*)d_in[16]; eg.ea_rcb=(const float*)d_in[17]; eg.Ercb= in_sizes[15];
  eg.rlt_s=(const int*)d_in[18]; eg.rlt_d=(const int*)d_in[19]; eg.ea_rlt=(const float*)d_in[20]; eg.Erlt= in_sizes[18];
  in.Wp_a=(const float*)d_in[21]; in.bp_a=(const float*)d_in[22];
  in.Wp_c=(const float*)d_in[23]; in.bp_c=(const float*)d_in[24];
  in.Wp_l=(const float*)d_in[25]; in.bp_l=(const float*)d_in[26];
  in.Wl1=(const float*)d_in[27]; in.bl1=(const float*)d_in[28];
  in.Wr1=(const float*)d_in[29]; in.br1=(const float*)d_in[30];
  in.We1=(const float*)d_in[31]; in.att1=(const float*)d_in[32]; in.bias1=(const float*)d_in[33];
  in.Wl2=(const float*)d_in[34]; in.bl2=(const float*)d_in[35];
  in.Wr2=(const float*)d_in[36]; in.br2=(const float*)d_in[37];
  in.We2=(const float*)d_in[38]; in.att2=(const float*)d_in[39]; in.bias2=(const float*)d_in[40];
  in.Wc1=(const float*)d_in[41]; in.bc1=(const float*)d_in[42];
  in.Wc2=(const float*)d_in[43]; in.bc2=(const float*)d_in[44];
  const int* qptr = (const int*)d_in[45];
  float* outp = (float*)d_out;

  char* p = (char*)d_ws;
  auto carve = [&](size_t n)->char*{ char* r = p; p += ((n + 255) & ~(size_t)255); return r; };
  WSP w;
  w.cnt  = (int*)carve(16*4);
  w.nf   = (int*)carve(3*4);
  w.l2rel=(int*)carve(N2MAX*4); w.l2src=(int*)carve(N2MAX*4);
  w.l2ea=(float*)carve(N2MAX*4); w.l2slot=(int*)carve(N2MAX*4);
  w.l1rel=(int*)carve(N1MAX*4); w.l1src=(int*)carve(N1MAX*4);
  w.l1dslot=(int*)carve(N1MAX*4); w.l1ea=(float*)carve(N1MAX*4);
  w.xr1a=(float*)carve((size_t)FAMAX*4*256*4);
  w.xr1c=(float*)carve((size_t)FCMAX*256*4);
  w.xr1l=(float*)carve((size_t)FLMAX*256*4);
  w.xl1e=(float*)carve((size_t)N1MAX*256*4);
  w.logit1=(float*)carve((size_t)N1MAX*2*4);
  w.xl2e=(float*)carve((size_t)N2MAX*128*4);
  w.logit2=(float*)carve(N2MAX*4);

  hipMemsetAsync(w.cnt, 0, 64, stream);   // counters + k45 ticket

  int quad2 = (eg.Esim + eg.Efw + eg.Ercb + eg.Erlt)/4 + 1;
  int b1 = (quad2 + 255)/256; if (b1 > 1024) b1 = 1024;
  k1<<<b1 + PFB, 256, 0, stream>>>(eg, in, qptr, w, b1);
  k2<<<PROJB + SCANB, 256, 0, stream>>>(in, eg, w, qptr);
  k3<<<256, 256, 0, stream>>>(in, w);
  k45<<<N2MAX, 256, 0, stream>>>(in, w, outp);
}